// Round 1
// baseline (363.147 us; speedup 1.0000x reference)
//
#include <hip/hip_runtime.h>
#include <hip/hip_bf16.h>

using bf16 = __hip_bfloat16;
typedef __attribute__((ext_vector_type(4))) float f32x4;
typedef __attribute__((ext_vector_type(8))) short short8;
typedef __attribute__((ext_vector_type(2))) unsigned int uint2v;
typedef __attribute__((ext_vector_type(4))) unsigned int uint4v;

#define DEVI static __device__ __forceinline__

DEVI unsigned short f2b(float f){
  unsigned int u = __float_as_uint(f);
  unsigned int r = (u + 0x7fffu + ((u >> 16) & 1u)) >> 16;
  return (unsigned short)r;
}
DEVI float b2f(unsigned short u){
  return __uint_as_float(((unsigned int)u) << 16);
}

DEVI void gload16(const void* g, void* l){
  __builtin_amdgcn_global_load_lds(
      (const __attribute__((address_space(1))) unsigned int*)g,
      (__attribute__((address_space(3))) unsigned int*)l, 16, 0, 0);
}

// ---- x [16][256][4096] f32 -> xT [16][4098][256] bf16 (row lp = l+1) ----
__global__ __launch_bounds__(256) void k_transpose_x(const float* __restrict__ x,
                                                     bf16* __restrict__ xt)
{
  __shared__ float tile[64][65];
  const int b = blockIdx.z, l0 = blockIdx.x*64, c0 = blockIdx.y*64;
  const int tid = threadIdx.x;
  {
    const int r = tid >> 2, q = tid & 3;
    const float* src = x + ((size_t)(b*256 + c0 + r))*4096 + l0 + q*16;
    #pragma unroll
    for (int j = 0; j < 4; ++j){
      const f32x4 v = *reinterpret_cast<const f32x4*>(src + j*4);
      #pragma unroll
      for (int e = 0; e < 4; ++e) tile[r][q*16 + j*4 + e] = v[e];
    }
  }
  __syncthreads();
  {
    const int jr = tid >> 2, cq = tid & 3;
    unsigned int w[8];
    #pragma unroll
    for (int e = 0; e < 8; ++e){
      const float lo = tile[cq*16 + 2*e][jr];
      const float hi = tile[cq*16 + 2*e + 1][jr];
      w[e] = (unsigned int)f2b(lo) | ((unsigned int)f2b(hi) << 16);
    }
    unsigned short* dst = (unsigned short*)xt + ((size_t)b*4098 + l0 + jr + 1)*256 + c0 + cq*16;
    uint4v a0 = {w[0],w[1],w[2],w[3]}, a1 = {w[4],w[5],w[6],w[7]};
    *reinterpret_cast<uint4v*>(dst)     = a0;
    *reinterpret_cast<uint4v*>(dst + 8) = a1;
  }
}

// ---- zero pad rows (lp=0 and lp=4097) of xT and h1T ----
__global__ void k_zero_pads(bf16* __restrict__ xt, bf16* __restrict__ h1t)
{
  const int b = blockIdx.x, tid = threadIdx.x;
  const size_t top = (size_t)b*4098*256 + tid;
  const size_t bot = (size_t)b*4098*256 + (size_t)4097*256 + tid;
  unsigned short* px = (unsigned short*)xt;
  unsigned short* ph = (unsigned short*)h1t;
  px[top] = 0; px[bot] = 0; ph[top] = 0; ph[bot] = 0;
}

// ---- f32 -> bf16 convert for 3 equally-sized tensors packed into dst ----
__global__ __launch_bounds__(256) void k_cvt3(const float* __restrict__ s0, const float* __restrict__ s1,
                                              const float* __restrict__ s2, bf16* __restrict__ dst, int n1)
{
  const size_t total = (size_t)3 * (size_t)n1 / 4;
  for (size_t i = (size_t)blockIdx.x*256 + threadIdx.x; i < total; i += (size_t)gridDim.x*256){
    const size_t e = i*4;
    const int which = (int)(e / (size_t)n1);
    const size_t off = e - (size_t)which*(size_t)n1;
    const float* s = which==0 ? s0 : which==1 ? s1 : s2;
    const f32x4 v = *reinterpret_cast<const f32x4*>(s + off);
    uint2v p;
    p[0] = (unsigned)f2b(v[0]) | ((unsigned)f2b(v[1])<<16);
    p[1] = (unsigned)f2b(v[2]) | ((unsigned)f2b(v[3])<<16);
    *reinterpret_cast<uint2v*>((unsigned short*)dst + e) = p;
  }
}

// ---- hypernet weight gen: Wt[i][b][t][o][c] = sum_h wb_i[c*3+t][h]*attb_i[b*256+o][h] + bias_i[c*3+t]
// GEMM: M=c (A = wb rows, stride 3), N=(b,o) (B^T = attb rows), K=1024
__global__ __launch_bounds__(256) void k_gen(const bf16* __restrict__ attb, const bf16* __restrict__ wbp,
                                             const float* __restrict__ bias0, const float* __restrict__ bias1,
                                             const float* __restrict__ bias2, bf16* __restrict__ Wt)
{
  __shared__ bf16 sA[128*32];
  __shared__ bf16 sB[128*32];
  const int iz = blockIdx.z, i = iz/3, t = iz - i*3;
  const int c0 = blockIdx.y*128, bo0 = blockIdx.x*128;
  const bf16* __restrict__ A  = wbp  + (size_t)i*768*1024;
  const bf16* __restrict__ Bt = attb + (size_t)i*4096*1024;
  const float* __restrict__ bias = (i==0) ? bias0 : (i==1) ? bias1 : bias2;
  const int tid = threadIdx.x, lane = tid & 63, wid = tid >> 6;
  const int wr = wid >> 1, wc = wid & 1;
  const int frow = lane & 15, kg = (lane >> 4)*8;
  f32x4 acc[4][4] = {};
  for (int k0 = 0; k0 < 1024; k0 += 32){
    __syncthreads();
    #pragma unroll
    for (int j = 0; j < 2; ++j){
      const int q = tid + j*256, r = q >> 2, cc = q & 3;
      gload16(A  + ((size_t)((c0 + r)*3 + t))*1024 + k0 + cc*8, sA + (size_t)q*8);
      gload16(Bt + ((size_t)(bo0 + r))*1024       + k0 + cc*8, sB + (size_t)q*8);
    }
    __syncthreads();
    short8 af[4], bf[4];
    #pragma unroll
    for (int f = 0; f < 4; ++f){
      af[f] = *reinterpret_cast<const short8*>(sA + (size_t)(wr*64 + f*16 + frow)*32 + kg);
      bf[f] = *reinterpret_cast<const short8*>(sB + (size_t)(wc*64 + f*16 + frow)*32 + kg);
    }
    #pragma unroll
    for (int fm = 0; fm < 4; ++fm)
      #pragma unroll
      for (int fn = 0; fn < 4; ++fn)
        acc[fm][fn] = __builtin_amdgcn_mfma_f32_16x16x32_bf16(af[fm], bf[fn], acc[fm][fn], 0, 0, 0);
  }
  #pragma unroll
  for (int fm = 0; fm < 4; ++fm){
    const int cb = c0 + wr*64 + fm*16 + (lane >> 4)*4;
    float bi[4];
    #pragma unroll
    for (int j = 0; j < 4; ++j) bi[j] = bias[(cb + j)*3 + t];
    #pragma unroll
    for (int fn = 0; fn < 4; ++fn){
      const int bo = bo0 + wc*64 + fn*16 + frow;
      const int bb = bo >> 8, o = bo & 255;
      unsigned short* dst = (unsigned short*)Wt + ((((size_t)(i*16 + bb)*3 + t)*256 + o)*256 + cb);
      uint2v p;
      p[0] = (unsigned)f2b(acc[fm][fn][0] + bi[0]) | ((unsigned)f2b(acc[fm][fn][1] + bi[1]) << 16);
      p[1] = (unsigned)f2b(acc[fm][fn][2] + bi[2]) | ((unsigned)f2b(acc[fm][fn][3] + bi[3]) << 16);
      *reinterpret_cast<uint2v*>(dst) = p;
    }
  }
}

// ---- b1[b*256+o] = att1[bo,:] . b1_w + b1_b ----
__global__ __launch_bounds__(256) void k_b1(const float* __restrict__ att1, const float* __restrict__ b1w,
                                            const float* __restrict__ b1b, float* __restrict__ out)
{
  const int m = blockIdx.x*4 + (threadIdx.x >> 6);
  const int lane = threadIdx.x & 63;
  const float* a = att1 + (size_t)m*1024;
  float s = 0.f;
  for (int k = lane*4; k < 1024; k += 256){
    const f32x4 v = *reinterpret_cast<const f32x4*>(a + k);
    const f32x4 w = *reinterpret_cast<const f32x4*>(b1w + k);
    s += v[0]*w[0] + v[1]*w[1] + v[2]*w[2] + v[3]*w[3];
  }
  #pragma unroll
  for (int d = 32; d > 0; d >>= 1) s += __shfl_down(s, d);
  if (lane == 0) out[m] = s + b1b[0];
}

// ---- att_conv: out[b][l][o] (+rowOff) = sum_t sum_c W[b][t][o][c] * Xt[b][l+t][c] ----
__global__ __launch_bounds__(256) void k_conv(const bf16* __restrict__ Xt, const bf16* __restrict__ W,
                                              const float* __restrict__ bias, bf16* __restrict__ out,
                                              int outBatchStride, int outRowOff, int applyRelu)
{
  __shared__ bf16 sA[128*32];
  __shared__ bf16 sB[128*32];
  const int b = blockIdx.z, o0 = blockIdx.y*128, l0 = blockIdx.x*128;
  const int tid = threadIdx.x, lane = tid & 63, wid = tid >> 6;
  const int wr = wid >> 1, wc = wid & 1;
  const int frow = lane & 15, kg = (lane >> 4)*8;
  f32x4 acc[4][4] = {};
  for (int s = 0; s < 24; ++s){
    const int t = s >> 3, c0 = (s & 7)*32;
    __syncthreads();
    #pragma unroll
    for (int j = 0; j < 2; ++j){
      const int q = tid + j*256, r = q >> 2, cc = q & 3;
      gload16(W  + (((size_t)b*3 + t)*256 + o0 + r)*256 + c0 + cc*8, sA + (size_t)q*8);
      gload16(Xt + ((size_t)b*4098 + l0 + t + r)*256    + c0 + cc*8, sB + (size_t)q*8);
    }
    __syncthreads();
    short8 af[4], bf[4];
    #pragma unroll
    for (int f = 0; f < 4; ++f){
      af[f] = *reinterpret_cast<const short8*>(sA + (size_t)(wr*64 + f*16 + frow)*32 + kg);
      bf[f] = *reinterpret_cast<const short8*>(sB + (size_t)(wc*64 + f*16 + frow)*32 + kg);
    }
    #pragma unroll
    for (int fm = 0; fm < 4; ++fm)
      #pragma unroll
      for (int fn = 0; fn < 4; ++fn)
        acc[fm][fn] = __builtin_amdgcn_mfma_f32_16x16x32_bf16(af[fm], bf[fn], acc[fm][fn], 0, 0, 0);
  }
  #pragma unroll
  for (int fm = 0; fm < 4; ++fm){
    const int ob = o0 + wr*64 + fm*16 + (lane >> 4)*4;
    float bi[4] = {0.f, 0.f, 0.f, 0.f};
    if (bias){
      const f32x4 bv = *reinterpret_cast<const f32x4*>(bias + b*256 + ob);
      bi[0]=bv[0]; bi[1]=bv[1]; bi[2]=bv[2]; bi[3]=bv[3];
    }
    #pragma unroll
    for (int fn = 0; fn < 4; ++fn){
      const int l = l0 + wc*64 + fn*16 + frow;
      float v[4];
      #pragma unroll
      for (int j = 0; j < 4; ++j){
        v[j] = acc[fm][fn][j] + bi[j];
        if (applyRelu) v[j] = fmaxf(v[j], 0.f);
      }
      unsigned short* dst = (unsigned short*)out +
          ((size_t)b*outBatchStride + (size_t)(l + outRowOff)*256 + ob);
      uint2v p;
      p[0] = (unsigned)f2b(v[0]) | ((unsigned)f2b(v[1]) << 16);
      p[1] = (unsigned)f2b(v[2]) | ((unsigned)f2b(v[3]) << 16);
      *reinterpret_cast<uint2v*>(dst) = p;
    }
  }
}

// ---- per-channel sum/sumsq over all (b,l) rows of yT [65536][256] ----
__global__ __launch_bounds__(256) void k_stats(const bf16* __restrict__ y, float* __restrict__ sum,
                                               float* __restrict__ sq)
{
  const int o = threadIdx.x;
  const unsigned short* p = (const unsigned short*)y + (size_t)blockIdx.x*256*256 + o;
  float s = 0.f, q = 0.f;
  for (int r = 0; r < 256; ++r){
    const float v = b2f(p[(size_t)r*256]);
    s += v; q += v*v;
  }
  atomicAdd(&sum[o], s);
  atomicAdd(&sq[o], q);
}

__global__ void k_bnfin(const float* __restrict__ sum, const float* __restrict__ sq,
                        const float* __restrict__ g, const float* __restrict__ bb,
                        float* __restrict__ scale, float* __restrict__ shift)
{
  const int o = threadIdx.x;
  const float inv = 1.f/65536.f;
  const float m = sum[o]*inv;
  const float v = fmaxf(sq[o]*inv - m*m, 0.f);
  const float sc = g[o] / sqrtf(v + 1e-5f);
  scale[o] = sc;
  shift[o] = bb[o] - m*sc;
}

// ---- h2T[b][lp][o] = relu(y2T[b][lp-1][o]*scale+shift), pads zeroed ----
__global__ __launch_bounds__(256) void k_norm2(const bf16* __restrict__ y, const float* __restrict__ scale,
                                               const float* __restrict__ shift, bf16* __restrict__ h)
{
  const int gr = blockIdx.x*8 + (threadIdx.x >> 5);
  const int oc = threadIdx.x & 31;
  const int b = gr / 4098, lp = gr - b*4098;
  unsigned short* dst = (unsigned short*)h + (size_t)gr*256 + oc*8;
  if (lp == 0 || lp == 4097){
    uint4v z = {0u,0u,0u,0u};
    *reinterpret_cast<uint4v*>(dst) = z;
    return;
  }
  const unsigned short* src = (const unsigned short*)y + ((size_t)b*4096 + (lp-1))*256 + oc*8;
  const uint4v in = *reinterpret_cast<const uint4v*>(src);
  const f32x4 sA0 = *reinterpret_cast<const f32x4*>(scale + oc*8);
  const f32x4 sA1 = *reinterpret_cast<const f32x4*>(scale + oc*8 + 4);
  const f32x4 hA0 = *reinterpret_cast<const f32x4*>(shift + oc*8);
  const f32x4 hA1 = *reinterpret_cast<const f32x4*>(shift + oc*8 + 4);
  uint4v ov;
  #pragma unroll
  for (int e = 0; e < 4; ++e){
    const unsigned int w = in[e];
    const float sc0 = (e<2) ? sA0[2*e] : sA1[2*e-4];
    const float sc1 = (e<2) ? sA0[2*e+1] : sA1[2*e-3];
    const float sh0 = (e<2) ? hA0[2*e] : hA1[2*e-4];
    const float sh1 = (e<2) ? hA0[2*e+1] : hA1[2*e-3];
    const float v0 = fmaxf(b2f((unsigned short)(w & 0xffffu))*sc0 + sh0, 0.f);
    const float v1 = fmaxf(b2f((unsigned short)(w >> 16))*sc1 + sh1, 0.f);
    ov[e] = (unsigned)f2b(v0) | ((unsigned)f2b(v1) << 16);
  }
  *reinterpret_cast<uint4v*>(dst) = ov;
}

// ---- h3 = relu(y3*scale+shift) in-place, plus per-(b,o) sums for SE ----
__global__ __launch_bounds__(256) void k_norm3(bf16* __restrict__ y, const float* __restrict__ scale,
                                               const float* __restrict__ shift, float* __restrict__ s_sum)
{
  __shared__ float red[8][256];
  const int tid = threadIdx.x;
  const int rr = tid >> 5, oc = tid & 31;
  const size_t row = (size_t)blockIdx.x*8 + rr;
  const int b = (int)(row >> 12);
  unsigned short* p = (unsigned short*)y + row*256 + oc*8;
  const uint4v in = *reinterpret_cast<const uint4v*>(p);
  const f32x4 sA0 = *reinterpret_cast<const f32x4*>(scale + oc*8);
  const f32x4 sA1 = *reinterpret_cast<const f32x4*>(scale + oc*8 + 4);
  const f32x4 hA0 = *reinterpret_cast<const f32x4*>(shift + oc*8);
  const f32x4 hA1 = *reinterpret_cast<const f32x4*>(shift + oc*8 + 4);
  uint4v ov;
  float loc[8];
  #pragma unroll
  for (int e = 0; e < 4; ++e){
    const unsigned int w = in[e];
    const float sc0 = (e<2) ? sA0[2*e] : sA1[2*e-4];
    const float sc1 = (e<2) ? sA0[2*e+1] : sA1[2*e-3];
    const float sh0 = (e<2) ? hA0[2*e] : hA1[2*e-4];
    const float sh1 = (e<2) ? hA0[2*e+1] : hA1[2*e-3];
    const float v0 = fmaxf(b2f((unsigned short)(w & 0xffffu))*sc0 + sh0, 0.f);
    const float v1 = fmaxf(b2f((unsigned short)(w >> 16))*sc1 + sh1, 0.f);
    loc[2*e] = v0; loc[2*e+1] = v1;
    ov[e] = (unsigned)f2b(v0) | ((unsigned)f2b(v1) << 16);
  }
  *reinterpret_cast<uint4v*>(p) = ov;
  #pragma unroll
  for (int j = 0; j < 8; ++j) red[rr][oc*8 + j] = loc[j];
  __syncthreads();
  const int o = tid;
  float tot = 0.f;
  #pragma unroll
  for (int r2 = 0; r2 < 8; ++r2) tot += red[r2][o];
  atomicAdd(&s_sum[(size_t)b*256 + o], tot);
}

// ---- SE: s2[b][o] = sigmoid(W2 @ relu(W1 @ mean + b1) + b2) ----
__global__ __launch_bounds__(256) void k_se(const float* __restrict__ s_sum, const float* __restrict__ w1,
                                            const float* __restrict__ b1, const float* __restrict__ w2,
                                            const float* __restrict__ b2, float* __restrict__ s2)
{
  __shared__ float sv[256];
  __shared__ float t1[256];
  const int b = blockIdx.x, o = threadIdx.x;
  sv[o] = s_sum[(size_t)b*256 + o] * (1.f/4096.f);
  __syncthreads();
  float a = b1[o];
  for (int c = 0; c < 256; ++c) a += w1[(size_t)o*256 + c] * sv[c];
  t1[o] = fmaxf(a, 0.f);
  __syncthreads();
  float a2 = b2[o];
  for (int c = 0; c < 256; ++c) a2 += w2[(size_t)o*256 + c] * t1[c];
  s2[(size_t)b*256 + o] = 1.f / (1.f + expf(-a2));
}

// ---- out[b][o][l] = relu(h3T[b][l][o]*s2[b][o] + x[b][o][l]) ----
__global__ __launch_bounds__(256) void k_final(const bf16* __restrict__ h3, const float* __restrict__ s2,
                                               const float* __restrict__ x, float* __restrict__ out)
{
  __shared__ float tile[64][65];
  const int b = blockIdx.z, o0 = blockIdx.y*64, l0 = blockIdx.x*64;
  const int tid = threadIdx.x;
  {
    const int r = tid >> 2, q = tid & 3;
    const unsigned short* src = (const unsigned short*)h3 + ((size_t)b*4096 + l0 + r)*256 + o0 + q*16;
    const uint4v a0 = *reinterpret_cast<const uint4v*>(src);
    const uint4v a1 = *reinterpret_cast<const uint4v*>(src + 8);
    #pragma unroll
    for (int e = 0; e < 4; ++e){
      tile[r][q*16 + 2*e]         = b2f((unsigned short)(a0[e] & 0xffffu));
      tile[r][q*16 + 2*e + 1]     = b2f((unsigned short)(a0[e] >> 16));
      tile[r][q*16 + 8 + 2*e]     = b2f((unsigned short)(a1[e] & 0xffffu));
      tile[r][q*16 + 8 + 2*e + 1] = b2f((unsigned short)(a1[e] >> 16));
    }
  }
  __syncthreads();
  {
    const int orow = tid >> 2, q = tid & 3;
    const int o = o0 + orow;
    const float sc = s2[(size_t)b*256 + o];
    const float* xs = x + ((size_t)b*256 + o)*4096 + l0 + q*16;
    float* dst = out + ((size_t)b*256 + o)*4096 + l0 + q*16;
    #pragma unroll
    for (int k = 0; k < 16; k += 4){
      const f32x4 xv = *reinterpret_cast<const f32x4*>(xs + k);
      f32x4 r;
      #pragma unroll
      for (int e = 0; e < 4; ++e)
        r[e] = fmaxf(tile[q*16 + k + e][orow]*sc + xv[e], 0.f);
      *reinterpret_cast<f32x4*>(dst + k) = r;
    }
  }
}

extern "C" void kernel_launch(void* const* d_in, const int* in_sizes, int n_in,
                              void* d_out, int out_size, void* d_ws, size_t ws_size,
                              hipStream_t stream)
{
  const float* x     = (const float*)d_in[0];
  const float* att1  = (const float*)d_in[1];
  const float* att2  = (const float*)d_in[2];
  const float* att3  = (const float*)d_in[3];
  const float* w1_w  = (const float*)d_in[4];
  const float* w1_b  = (const float*)d_in[5];
  const float* w2_w  = (const float*)d_in[6];
  const float* w2_b  = (const float*)d_in[7];
  const float* w3_w  = (const float*)d_in[8];
  const float* w3_b  = (const float*)d_in[9];
  const float* b1_w  = (const float*)d_in[10];
  const float* b1_b  = (const float*)d_in[11];
  const float* bn2_w = (const float*)d_in[12];
  const float* bn2_b = (const float*)d_in[13];
  const float* bn3_w = (const float*)d_in[14];
  const float* bn3_b = (const float*)d_in[15];
  const float* se1_w = (const float*)d_in[16];
  const float* se1_b = (const float*)d_in[17];
  const float* se2_w = (const float*)d_in[18];
  const float* se2_b = (const float*)d_in[19];

  char* ws = (char*)d_ws;
  // workspace layout (bytes)
  bf16*  xT   = (bf16*)(ws + 0);           // [16][4098][256]  (reused as y3T/h3T)
  bf16*  h1T  = (bf16*)(ws + 33570816);    // [16][4098][256]
  bf16*  y2T  = (bf16*)(ws + 67141632);    // [16][4096][256]
  bf16*  h2T  = (bf16*)(ws + 100696064);   // [16][4098][256]
  bf16*  Wt   = (bf16*)(ws + 134266880);   // [3][16][3][256][256]
  bf16*  attb = (bf16*)(ws + 153141248);   // [3][4096][1024]
  bf16*  wb   = (bf16*)(ws + 178307072);   // [3][768][1024]
  float* b1v  = (float*)(ws + 183025664);  // [4096]
  float* st   = (float*)(ws + 183042048);
  float* bn2sum = st;          // 256
  float* bn2sq  = st + 256;
  float* bn3sum = st + 512;
  float* bn3sq  = st + 768;
  float* s_sum  = st + 1024;   // 4096
  float* scale2 = st + 5120;
  float* shift2 = st + 5376;
  float* scale3 = st + 5632;
  float* shift3 = st + 5888;
  float* s2v    = st + 6144;   // 4096
  bf16*  y3T  = (bf16*)(ws + 0);           // overlay on xT (dead after conv1)

  // zero accumulators (bn2/bn3 sums + s_sum = 5120 floats)
  hipMemsetAsync(st, 0, 5120*sizeof(float), stream);

  k_transpose_x<<<dim3(64,4,16),256,0,stream>>>(x, xT);
  k_zero_pads<<<16,256,0,stream>>>(xT, h1T);
  k_cvt3<<<2048,256,0,stream>>>(att1, att2, att3, attb, 4096*1024);
  k_cvt3<<<512,256,0,stream>>>(w1_w, w2_w, w3_w, wb, 768*1024);
  k_gen<<<dim3(32,2,9),256,0,stream>>>(attb, wb, w1_b, w2_b, w3_b, Wt);
  k_b1<<<1024,256,0,stream>>>(att1, b1_w, b1_b, b1v);

  k_conv<<<dim3(32,2,16),256,0,stream>>>(xT,  Wt,                               b1v,     h1T, 4098*256, 1, 1);
  k_conv<<<dim3(32,2,16),256,0,stream>>>(h1T, Wt + (size_t)1*16*3*256*256, nullptr, y2T, 4096*256, 0, 0);
  k_stats<<<256,256,0,stream>>>(y2T, bn2sum, bn2sq);
  k_bnfin<<<1,256,0,stream>>>(bn2sum, bn2sq, bn2_w, bn2_b, scale2, shift2);
  k_norm2<<<8196,256,0,stream>>>(y2T, scale2, shift2, h2T);
  k_conv<<<dim3(32,2,16),256,0,stream>>>(h2T, Wt + (size_t)2*16*3*256*256, nullptr, y3T, 4096*256, 0, 0);
  k_stats<<<256,256,0,stream>>>(y3T, bn3sum, bn3sq);
  k_bnfin<<<1,256,0,stream>>>(bn3sum, bn3sq, bn3_w, bn3_b, scale3, shift3);
  k_norm3<<<8192,256,0,stream>>>(y3T, scale3, shift3, s_sum);
  k_se<<<16,256,0,stream>>>(s_sum, se1_w, se1_b, se2_w, se2_b, s2v);
  k_final<<<dim3(64,4,16),256,0,stream>>>((const bf16*)y3T, s2v, x, (float*)d_out);
}

// Round 2
// 350.841 us; speedup vs baseline: 1.0351x; 1.0351x over previous
//
#include <hip/hip_runtime.h>
#include <hip/hip_bf16.h>

using bf16 = __hip_bfloat16;
typedef __attribute__((ext_vector_type(4))) float f32x4;
typedef __attribute__((ext_vector_type(8))) short short8;
typedef __attribute__((ext_vector_type(2))) unsigned int uint2v;
typedef __attribute__((ext_vector_type(4))) unsigned int uint4v;

#define DEVI static __device__ __forceinline__

DEVI unsigned short f2b(float f){
  unsigned int u = __float_as_uint(f);
  unsigned int r = (u + 0x7fffu + ((u >> 16) & 1u)) >> 16;
  return (unsigned short)r;
}
DEVI float b2f(unsigned short u){
  return __uint_as_float(((unsigned int)u) << 16);
}

DEVI void gload16(const void* g, void* l){
  __builtin_amdgcn_global_load_lds(
      (const __attribute__((address_space(1))) unsigned int*)g,
      (__attribute__((address_space(3))) unsigned int*)l, 16, 0, 0);
}

// ---- x [16][256][4096] f32 -> xT [16][4098][256] bf16 (row lp = l+1) ----
__global__ __launch_bounds__(256) void k_transpose_x(const float* __restrict__ x,
                                                     bf16* __restrict__ xt)
{
  __shared__ float tile[64][65];
  const int b = blockIdx.z, l0 = blockIdx.x*64, c0 = blockIdx.y*64;
  const int tid = threadIdx.x;
  {
    const int r = tid >> 2, q = tid & 3;
    const float* src = x + ((size_t)(b*256 + c0 + r))*4096 + l0 + q*16;
    #pragma unroll
    for (int j = 0; j < 4; ++j){
      const f32x4 v = *reinterpret_cast<const f32x4*>(src + j*4);
      #pragma unroll
      for (int e = 0; e < 4; ++e) tile[r][q*16 + j*4 + e] = v[e];
    }
  }
  __syncthreads();
  {
    const int jr = tid >> 2, cq = tid & 3;
    unsigned int w[8];
    #pragma unroll
    for (int e = 0; e < 8; ++e){
      const float lo = tile[cq*16 + 2*e][jr];
      const float hi = tile[cq*16 + 2*e + 1][jr];
      w[e] = (unsigned int)f2b(lo) | ((unsigned int)f2b(hi) << 16);
    }
    unsigned short* dst = (unsigned short*)xt + ((size_t)b*4098 + l0 + jr + 1)*256 + c0 + cq*16;
    uint4v a0 = {w[0],w[1],w[2],w[3]}, a1 = {w[4],w[5],w[6],w[7]};
    *reinterpret_cast<uint4v*>(dst)     = a0;
    *reinterpret_cast<uint4v*>(dst + 8) = a1;
  }
}

// ---- zero pad rows (lp=0 and lp=4097) of xT and h1T ----
__global__ void k_zero_pads(bf16* __restrict__ xt, bf16* __restrict__ h1t)
{
  const int b = blockIdx.x, tid = threadIdx.x;
  const size_t top = (size_t)b*4098*256 + tid;
  const size_t bot = (size_t)b*4098*256 + (size_t)4097*256 + tid;
  unsigned short* px = (unsigned short*)xt;
  unsigned short* ph = (unsigned short*)h1t;
  px[top] = 0; px[bot] = 0; ph[top] = 0; ph[bot] = 0;
}

// ---- f32 -> bf16 convert for 3 equally-sized tensors packed into dst ----
__global__ __launch_bounds__(256) void k_cvt3(const float* __restrict__ s0, const float* __restrict__ s1,
                                              const float* __restrict__ s2, bf16* __restrict__ dst, int n1)
{
  const size_t total = (size_t)3 * (size_t)n1 / 4;
  for (size_t i = (size_t)blockIdx.x*256 + threadIdx.x; i < total; i += (size_t)gridDim.x*256){
    const size_t e = i*4;
    const int which = (int)(e / (size_t)n1);
    const size_t off = e - (size_t)which*(size_t)n1;
    const float* s = which==0 ? s0 : which==1 ? s1 : s2;
    const f32x4 v = *reinterpret_cast<const f32x4*>(s + off);
    uint2v p;
    p[0] = (unsigned)f2b(v[0]) | ((unsigned)f2b(v[1])<<16);
    p[1] = (unsigned)f2b(v[2]) | ((unsigned)f2b(v[3])<<16);
    *reinterpret_cast<uint2v*>((unsigned short*)dst + e) = p;
  }
}

// ---- hypernet weight gen: Wt[i][b][t][o][c] = sum_h wb_i[c*3+t][h]*attb_i[b*256+o][h] + bias_i[c*3+t]
// GEMM: M=c (A = wb rows, stride 3), N=(b,o) (B^T = attb rows), K=1024
// LDS bank-conflict fix: 16B-slot swizzle slot' = slot ^ ((row>>1)&3), applied to
// the pre-swizzled GLOBAL source (gload_lds dest must stay linear) and to the read.
__global__ __launch_bounds__(256) void k_gen(const bf16* __restrict__ attb, const bf16* __restrict__ wbp,
                                             const float* __restrict__ bias0, const float* __restrict__ bias1,
                                             const float* __restrict__ bias2, bf16* __restrict__ Wt)
{
  __shared__ bf16 sA[128*32];
  __shared__ bf16 sB[128*32];
  const int iz = blockIdx.z, i = iz/3, t = iz - i*3;
  const int c0 = blockIdx.y*128, bo0 = blockIdx.x*128;
  const bf16* __restrict__ A  = wbp  + (size_t)i*768*1024;
  const bf16* __restrict__ Bt = attb + (size_t)i*4096*1024;
  const float* __restrict__ bias = (i==0) ? bias0 : (i==1) ? bias1 : bias2;
  const int tid = threadIdx.x, lane = tid & 63, wid = tid >> 6;
  const int wr = wid >> 1, wc = wid & 1;
  const int frow = lane & 15;
  const int sel = (frow >> 1) & 3;
  const int kgs = ((lane >> 4) ^ sel) * 8;
  f32x4 acc[4][4] = {};
  for (int k0 = 0; k0 < 1024; k0 += 32){
    __syncthreads();
    #pragma unroll
    for (int j = 0; j < 2; ++j){
      const int q = tid + j*256, r = q >> 2;
      const int cc = (q & 3) ^ ((r >> 1) & 3);   // pre-swizzled source slot
      gload16(A  + ((size_t)((c0 + r)*3 + t))*1024 + k0 + cc*8, sA + (size_t)q*8);
      gload16(Bt + ((size_t)(bo0 + r))*1024       + k0 + cc*8, sB + (size_t)q*8);
    }
    __syncthreads();
    short8 af[4], bf[4];
    #pragma unroll
    for (int f = 0; f < 4; ++f){
      af[f] = *reinterpret_cast<const short8*>(sA + (size_t)(wr*64 + f*16 + frow)*32 + kgs);
      bf[f] = *reinterpret_cast<const short8*>(sB + (size_t)(wc*64 + f*16 + frow)*32 + kgs);
    }
    #pragma unroll
    for (int fm = 0; fm < 4; ++fm)
      #pragma unroll
      for (int fn = 0; fn < 4; ++fn)
        acc[fm][fn] = __builtin_amdgcn_mfma_f32_16x16x32_bf16(af[fm], bf[fn], acc[fm][fn], 0, 0, 0);
  }
  #pragma unroll
  for (int fm = 0; fm < 4; ++fm){
    const int cb = c0 + wr*64 + fm*16 + (lane >> 4)*4;
    float bi[4];
    #pragma unroll
    for (int j = 0; j < 4; ++j) bi[j] = bias[(cb + j)*3 + t];
    #pragma unroll
    for (int fn = 0; fn < 4; ++fn){
      const int bo = bo0 + wc*64 + fn*16 + frow;
      const int bb = bo >> 8, o = bo & 255;
      unsigned short* dst = (unsigned short*)Wt + ((((size_t)(i*16 + bb)*3 + t)*256 + o)*256 + cb);
      uint2v p;
      p[0] = (unsigned)f2b(acc[fm][fn][0] + bi[0]) | ((unsigned)f2b(acc[fm][fn][1] + bi[1]) << 16);
      p[1] = (unsigned)f2b(acc[fm][fn][2] + bi[2]) | ((unsigned)f2b(acc[fm][fn][3] + bi[3]) << 16);
      *reinterpret_cast<uint2v*>(dst) = p;
    }
  }
}

// ---- b1[b*256+o] = att1[bo,:] . b1_w + b1_b ----
__global__ __launch_bounds__(256) void k_b1(const float* __restrict__ att1, const float* __restrict__ b1w,
                                            const float* __restrict__ b1b, float* __restrict__ out)
{
  const int m = blockIdx.x*4 + (threadIdx.x >> 6);
  const int lane = threadIdx.x & 63;
  const float* a = att1 + (size_t)m*1024;
  float s = 0.f;
  for (int k = lane*4; k < 1024; k += 256){
    const f32x4 v = *reinterpret_cast<const f32x4*>(a + k);
    const f32x4 w = *reinterpret_cast<const f32x4*>(b1w + k);
    s += v[0]*w[0] + v[1]*w[1] + v[2]*w[2] + v[3]*w[3];
  }
  #pragma unroll
  for (int d = 32; d > 0; d >>= 1) s += __shfl_down(s, d);
  if (lane == 0) out[m] = s + b1b[0];
}

// ---- att_conv: out[b][l][o] (+rowOff) = sum_t sum_c W[b][t][o][c] * Xt[b][l+t][c]
// Swizzled LDS (as in k_gen). Optionally fuses BN sum/sumsq accumulation
// (per-channel over the stored values) into the epilogue.
__global__ __launch_bounds__(256) void k_conv(const bf16* __restrict__ Xt, const bf16* __restrict__ W,
                                              const float* __restrict__ bias, bf16* __restrict__ out,
                                              int outBatchStride, int outRowOff, int applyRelu,
                                              float* __restrict__ statSum, float* __restrict__ statSq)
{
  __shared__ bf16 sA[128*32];
  __shared__ bf16 sB[128*32];
  const int b = blockIdx.z, o0 = blockIdx.y*128, l0 = blockIdx.x*128;
  const int tid = threadIdx.x, lane = tid & 63, wid = tid >> 6;
  const int wr = wid >> 1, wc = wid & 1;
  const int frow = lane & 15;
  const int sel = (frow >> 1) & 3;
  const int kgs = ((lane >> 4) ^ sel) * 8;
  f32x4 acc[4][4] = {};
  for (int s = 0; s < 24; ++s){
    const int t = s >> 3, c0 = (s & 7)*32;
    __syncthreads();
    #pragma unroll
    for (int j = 0; j < 2; ++j){
      const int q = tid + j*256, r = q >> 2;
      const int cc = (q & 3) ^ ((r >> 1) & 3);   // pre-swizzled source slot
      gload16(W  + (((size_t)b*3 + t)*256 + o0 + r)*256 + c0 + cc*8, sA + (size_t)q*8);
      gload16(Xt + ((size_t)b*4098 + l0 + t + r)*256    + c0 + cc*8, sB + (size_t)q*8);
    }
    __syncthreads();
    short8 af[4], bf[4];
    #pragma unroll
    for (int f = 0; f < 4; ++f){
      af[f] = *reinterpret_cast<const short8*>(sA + (size_t)(wr*64 + f*16 + frow)*32 + kgs);
      bf[f] = *reinterpret_cast<const short8*>(sB + (size_t)(wc*64 + f*16 + frow)*32 + kgs);
    }
    #pragma unroll
    for (int fm = 0; fm < 4; ++fm)
      #pragma unroll
      for (int fn = 0; fn < 4; ++fn)
        acc[fm][fn] = __builtin_amdgcn_mfma_f32_16x16x32_bf16(af[fm], bf[fn], acc[fm][fn], 0, 0, 0);
  }
  float cs[4][4] = {{0.f}}, cq[4][4] = {{0.f}};
  #pragma unroll
  for (int fm = 0; fm < 4; ++fm){
    const int ob = o0 + wr*64 + fm*16 + (lane >> 4)*4;
    float bi[4] = {0.f, 0.f, 0.f, 0.f};
    if (bias){
      const f32x4 bv = *reinterpret_cast<const f32x4*>(bias + b*256 + ob);
      bi[0]=bv[0]; bi[1]=bv[1]; bi[2]=bv[2]; bi[3]=bv[3];
    }
    #pragma unroll
    for (int fn = 0; fn < 4; ++fn){
      const int l = l0 + wc*64 + fn*16 + frow;
      float v[4];
      #pragma unroll
      for (int j = 0; j < 4; ++j){
        v[j] = acc[fm][fn][j] + bi[j];
        if (applyRelu) v[j] = fmaxf(v[j], 0.f);
        cs[fm][j] += v[j];
        cq[fm][j] += v[j]*v[j];
      }
      unsigned short* dst = (unsigned short*)out +
          ((size_t)b*outBatchStride + (size_t)(l + outRowOff)*256 + ob);
      uint2v p;
      p[0] = (unsigned)f2b(v[0]) | ((unsigned)f2b(v[1]) << 16);
      p[1] = (unsigned)f2b(v[2]) | ((unsigned)f2b(v[3]) << 16);
      *reinterpret_cast<uint2v*>(dst) = p;
    }
  }
  if (statSum){
    // reduce across the 16 l-lanes (frow) sharing each channel set
    #pragma unroll
    for (int fm = 0; fm < 4; ++fm)
      #pragma unroll
      for (int j = 0; j < 4; ++j){
        #pragma unroll
        for (int d = 1; d < 16; d <<= 1){
          cs[fm][j] += __shfl_xor(cs[fm][j], d);
          cq[fm][j] += __shfl_xor(cq[fm][j], d);
        }
      }
    __syncthreads();                       // LDS reads all done -> reuse as scratch
    float* ls = (float*)sA;                // [4 waves][64 ch]
    float* lq = (float*)sB;
    if (frow == 0){
      const int grp = lane >> 4;
      #pragma unroll
      for (int fm = 0; fm < 4; ++fm)
        #pragma unroll
        for (int j = 0; j < 4; ++j){
          ls[wid*64 + fm*16 + grp*4 + j] = cs[fm][j];
          lq[wid*64 + fm*16 + grp*4 + j] = cq[fm][j];
        }
    }
    __syncthreads();
    if (tid < 128){
      const int wrg = tid >> 6, c6 = tid & 63;
      const float s  = ls[(wrg*2)*64 + c6] + ls[(wrg*2+1)*64 + c6];
      const float qq = lq[(wrg*2)*64 + c6] + lq[(wrg*2+1)*64 + c6];
      atomicAdd(statSum + o0 + tid, s);
      atomicAdd(statSq  + o0 + tid, qq);
    }
  }
}

__global__ void k_bnfin(const float* __restrict__ sum, const float* __restrict__ sq,
                        const float* __restrict__ g, const float* __restrict__ bb,
                        float* __restrict__ scale, float* __restrict__ shift)
{
  const int o = threadIdx.x;
  const float inv = 1.f/65536.f;
  const float m = sum[o]*inv;
  const float v = fmaxf(sq[o]*inv - m*m, 0.f);
  const float sc = g[o] / sqrtf(v + 1e-5f);
  scale[o] = sc;
  shift[o] = bb[o] - m*sc;
}

// ---- h2T[b][lp][o] = relu(y2T[b][lp-1][o]*scale+shift), pads zeroed ----
__global__ __launch_bounds__(256) void k_norm2(const bf16* __restrict__ y, const float* __restrict__ scale,
                                               const float* __restrict__ shift, bf16* __restrict__ h)
{
  const int gr = blockIdx.x*8 + (threadIdx.x >> 5);
  const int oc = threadIdx.x & 31;
  const int b = gr / 4098, lp = gr - b*4098;
  unsigned short* dst = (unsigned short*)h + (size_t)gr*256 + oc*8;
  if (lp == 0 || lp == 4097){
    uint4v z = {0u,0u,0u,0u};
    *reinterpret_cast<uint4v*>(dst) = z;
    return;
  }
  const unsigned short* src = (const unsigned short*)y + ((size_t)b*4096 + (lp-1))*256 + oc*8;
  const uint4v in = *reinterpret_cast<const uint4v*>(src);
  const f32x4 sA0 = *reinterpret_cast<const f32x4*>(scale + oc*8);
  const f32x4 sA1 = *reinterpret_cast<const f32x4*>(scale + oc*8 + 4);
  const f32x4 hA0 = *reinterpret_cast<const f32x4*>(shift + oc*8);
  const f32x4 hA1 = *reinterpret_cast<const f32x4*>(shift + oc*8 + 4);
  uint4v ov;
  #pragma unroll
  for (int e = 0; e < 4; ++e){
    const unsigned int w = in[e];
    const float sc0 = (e<2) ? sA0[2*e] : sA1[2*e-4];
    const float sc1 = (e<2) ? sA0[2*e+1] : sA1[2*e-3];
    const float sh0 = (e<2) ? hA0[2*e] : hA1[2*e-4];
    const float sh1 = (e<2) ? hA0[2*e+1] : hA1[2*e-3];
    const float v0 = fmaxf(b2f((unsigned short)(w & 0xffffu))*sc0 + sh0, 0.f);
    const float v1 = fmaxf(b2f((unsigned short)(w >> 16))*sc1 + sh1, 0.f);
    ov[e] = (unsigned)f2b(v0) | ((unsigned)f2b(v1) << 16);
  }
  *reinterpret_cast<uint4v*>(dst) = ov;
}

// ---- h3 = relu(y3*scale+shift) in-place, plus per-(b,o) sums for SE ----
__global__ __launch_bounds__(256) void k_norm3(bf16* __restrict__ y, const float* __restrict__ scale,
                                               const float* __restrict__ shift, float* __restrict__ s_sum)
{
  __shared__ float red[8][256];
  const int tid = threadIdx.x;
  const int rr = tid >> 5, oc = tid & 31;
  const size_t row = (size_t)blockIdx.x*8 + rr;
  const int b = (int)(row >> 12);
  unsigned short* p = (unsigned short*)y + row*256 + oc*8;
  const uint4v in = *reinterpret_cast<const uint4v*>(p);
  const f32x4 sA0 = *reinterpret_cast<const f32x4*>(scale + oc*8);
  const f32x4 sA1 = *reinterpret_cast<const f32x4*>(scale + oc*8 + 4);
  const f32x4 hA0 = *reinterpret_cast<const f32x4*>(shift + oc*8);
  const f32x4 hA1 = *reinterpret_cast<const f32x4*>(shift + oc*8 + 4);
  uint4v ov;
  float loc[8];
  #pragma unroll
  for (int e = 0; e < 4; ++e){
    const unsigned int w = in[e];
    const float sc0 = (e<2) ? sA0[2*e] : sA1[2*e-4];
    const float sc1 = (e<2) ? sA0[2*e+1] : sA1[2*e-3];
    const float sh0 = (e<2) ? hA0[2*e] : hA1[2*e-4];
    const float sh1 = (e<2) ? hA0[2*e+1] : hA1[2*e-3];
    const float v0 = fmaxf(b2f((unsigned short)(w & 0xffffu))*sc0 + sh0, 0.f);
    const float v1 = fmaxf(b2f((unsigned short)(w >> 16))*sc1 + sh1, 0.f);
    loc[2*e] = v0; loc[2*e+1] = v1;
    ov[e] = (unsigned)f2b(v0) | ((unsigned)f2b(v1) << 16);
  }
  *reinterpret_cast<uint4v*>(p) = ov;
  #pragma unroll
  for (int j = 0; j < 8; ++j) red[rr][oc*8 + j] = loc[j];
  __syncthreads();
  const int o = tid;
  float tot = 0.f;
  #pragma unroll
  for (int r2 = 0; r2 < 8; ++r2) tot += red[r2][o];
  atomicAdd(&s_sum[(size_t)b*256 + o], tot);
}

// ---- SE: s2[b][o] = sigmoid(W2 @ relu(W1 @ mean + b1) + b2) ----
__global__ __launch_bounds__(256) void k_se(const float* __restrict__ s_sum, const float* __restrict__ w1,
                                            const float* __restrict__ b1, const float* __restrict__ w2,
                                            const float* __restrict__ b2, float* __restrict__ s2)
{
  __shared__ float sv[256];
  __shared__ float t1[256];
  const int b = blockIdx.x, o = threadIdx.x;
  sv[o] = s_sum[(size_t)b*256 + o] * (1.f/4096.f);
  __syncthreads();
  float a = b1[o];
  for (int c = 0; c < 256; ++c) a += w1[(size_t)o*256 + c] * sv[c];
  t1[o] = fmaxf(a, 0.f);
  __syncthreads();
  float a2 = b2[o];
  for (int c = 0; c < 256; ++c) a2 += w2[(size_t)o*256 + c] * t1[c];
  s2[(size_t)b*256 + o] = 1.f / (1.f + expf(-a2));
}

// ---- out[b][o][l] = relu(h3T[b][l][o]*s2[b][o] + x[b][o][l]) ----
__global__ __launch_bounds__(256) void k_final(const bf16* __restrict__ h3, const float* __restrict__ s2,
                                               const float* __restrict__ x, float* __restrict__ out)
{
  __shared__ float tile[64][65];
  const int b = blockIdx.z, o0 = blockIdx.y*64, l0 = blockIdx.x*64;
  const int tid = threadIdx.x;
  {
    const int r = tid >> 2, q = tid & 3;
    const unsigned short* src = (const unsigned short*)h3 + ((size_t)b*4096 + l0 + r)*256 + o0 + q*16;
    const uint4v a0 = *reinterpret_cast<const uint4v*>(src);
    const uint4v a1 = *reinterpret_cast<const uint4v*>(src + 8);
    #pragma unroll
    for (int e = 0; e < 4; ++e){
      tile[r][q*16 + 2*e]         = b2f((unsigned short)(a0[e] & 0xffffu));
      tile[r][q*16 + 2*e + 1]     = b2f((unsigned short)(a0[e] >> 16));
      tile[r][q*16 + 8 + 2*e]     = b2f((unsigned short)(a1[e] & 0xffffu));
      tile[r][q*16 + 8 + 2*e + 1] = b2f((unsigned short)(a1[e] >> 16));
    }
  }
  __syncthreads();
  {
    const int orow = tid >> 2, q = tid & 3;
    const int o = o0 + orow;
    const float sc = s2[(size_t)b*256 + o];
    const float* xs = x + ((size_t)b*256 + o)*4096 + l0 + q*16;
    float* dst = out + ((size_t)b*256 + o)*4096 + l0 + q*16;
    #pragma unroll
    for (int k = 0; k < 16; k += 4){
      const f32x4 xv = *reinterpret_cast<const f32x4*>(xs + k);
      f32x4 r;
      #pragma unroll
      for (int e = 0; e < 4; ++e)
        r[e] = fmaxf(tile[q*16 + k + e][orow]*sc + xv[e], 0.f);
      *reinterpret_cast<f32x4*>(dst + k) = r;
    }
  }
}

extern "C" void kernel_launch(void* const* d_in, const int* in_sizes, int n_in,
                              void* d_out, int out_size, void* d_ws, size_t ws_size,
                              hipStream_t stream)
{
  const float* x     = (const float*)d_in[0];
  const float* att1  = (const float*)d_in[1];
  const float* att2  = (const float*)d_in[2];
  const float* att3  = (const float*)d_in[3];
  const float* w1_w  = (const float*)d_in[4];
  const float* w1_b  = (const float*)d_in[5];
  const float* w2_w  = (const float*)d_in[6];
  const float* w2_b  = (const float*)d_in[7];
  const float* w3_w  = (const float*)d_in[8];
  const float* w3_b  = (const float*)d_in[9];
  const float* b1_w  = (const float*)d_in[10];
  const float* b1_b  = (const float*)d_in[11];
  const float* bn2_w = (const float*)d_in[12];
  const float* bn2_b = (const float*)d_in[13];
  const float* bn3_w = (const float*)d_in[14];
  const float* bn3_b = (const float*)d_in[15];
  const float* se1_w = (const float*)d_in[16];
  const float* se1_b = (const float*)d_in[17];
  const float* se2_w = (const float*)d_in[18];
  const float* se2_b = (const float*)d_in[19];

  char* ws = (char*)d_ws;
  // workspace layout (bytes)
  bf16*  xT   = (bf16*)(ws + 0);           // [16][4098][256]  (reused as y3T/h3T)
  bf16*  h1T  = (bf16*)(ws + 33570816);    // [16][4098][256]
  bf16*  y2T  = (bf16*)(ws + 67141632);    // [16][4096][256]
  bf16*  h2T  = (bf16*)(ws + 100696064);   // [16][4098][256]
  bf16*  Wt   = (bf16*)(ws + 134266880);   // [3][16][3][256][256]
  bf16*  attb = (bf16*)(ws + 153141248);   // [3][4096][1024]
  bf16*  wb   = (bf16*)(ws + 178307072);   // [3][768][1024]
  float* b1v  = (float*)(ws + 183025664);  // [4096]
  float* st   = (float*)(ws + 183042048);
  float* bn2sum = st;          // 256
  float* bn2sq  = st + 256;
  float* bn3sum = st + 512;
  float* bn3sq  = st + 768;
  float* s_sum  = st + 1024;   // 4096
  float* scale2 = st + 5120;
  float* shift2 = st + 5376;
  float* scale3 = st + 5632;
  float* shift3 = st + 5888;
  float* s2v    = st + 6144;   // 4096
  bf16*  y3T  = (bf16*)(ws + 0);           // overlay on xT (dead after conv1)

  // zero accumulators (bn2/bn3 sums + s_sum = 5120 floats)
  hipMemsetAsync(st, 0, 5120*sizeof(float), stream);

  k_transpose_x<<<dim3(64,4,16),256,0,stream>>>(x, xT);
  k_zero_pads<<<16,256,0,stream>>>(xT, h1T);
  k_cvt3<<<2048,256,0,stream>>>(att1, att2, att3, attb, 4096*1024);
  k_cvt3<<<512,256,0,stream>>>(w1_w, w2_w, w3_w, wb, 768*1024);
  k_gen<<<dim3(32,2,9),256,0,stream>>>(attb, wb, w1_b, w2_b, w3_b, Wt);
  k_b1<<<1024,256,0,stream>>>(att1, b1_w, b1_b, b1v);

  k_conv<<<dim3(32,2,16),256,0,stream>>>(xT,  Wt,                           b1v,     h1T, 4098*256, 1, 1, nullptr, nullptr);
  k_conv<<<dim3(32,2,16),256,0,stream>>>(h1T, Wt + (size_t)1*16*3*256*256,  nullptr, y2T, 4096*256, 0, 0, bn2sum, bn2sq);
  k_bnfin<<<1,256,0,stream>>>(bn2sum, bn2sq, bn2_w, bn2_b, scale2, shift2);
  k_norm2<<<8196,256,0,stream>>>(y2T, scale2, shift2, h2T);
  k_conv<<<dim3(32,2,16),256,0,stream>>>(h2T, Wt + (size_t)2*16*3*256*256,  nullptr, y3T, 4096*256, 0, 0, bn3sum, bn3sq);
  k_bnfin<<<1,256,0,stream>>>(bn3sum, bn3sq, bn3_w, bn3_b, scale3, shift3);
  k_norm3<<<8192,256,0,stream>>>(y3T, scale3, shift3, s_sum);
  k_se<<<16,256,0,stream>>>(s_sum, se1_w, se1_b, se2_w, se2_b, s2v);
  k_final<<<dim3(64,4,16),256,0,stream>>>((const bf16*)y3T, s2v, x, (float*)d_out);
}

// Round 3
// 339.721 us; speedup vs baseline: 1.0690x; 1.0327x over previous
//
#include <hip/hip_runtime.h>
#include <hip/hip_bf16.h>

using bf16 = __hip_bfloat16;
typedef __attribute__((ext_vector_type(4))) float f32x4;
typedef __attribute__((ext_vector_type(8))) short short8;
typedef __attribute__((ext_vector_type(2))) unsigned int uint2v;
typedef __attribute__((ext_vector_type(4))) unsigned int uint4v;

#define DEVI static __device__ __forceinline__

DEVI unsigned short f2b(float f){
  unsigned int u = __float_as_uint(f);
  unsigned int r = (u + 0x7fffu + ((u >> 16) & 1u)) >> 16;
  return (unsigned short)r;
}
DEVI float b2f(unsigned short u){
  return __uint_as_float(((unsigned int)u) << 16);
}

DEVI void gload16(const void* g, void* l){
  __builtin_amdgcn_global_load_lds(
      (const __attribute__((address_space(1))) unsigned int*)g,
      (__attribute__((address_space(3))) unsigned int*)l, 16, 0, 0);
}

// ---- x [16][256][4096] f32 -> xT [16][4098][256] bf16 (row lp = l+1) ----
__global__ __launch_bounds__(256) void k_transpose_x(const float* __restrict__ x,
                                                     bf16* __restrict__ xt)
{
  __shared__ float tile[64][65];
  const int b = blockIdx.z, l0 = blockIdx.x*64, c0 = blockIdx.y*64;
  const int tid = threadIdx.x;
  {
    const int r = tid >> 2, q = tid & 3;
    const float* src = x + ((size_t)(b*256 + c0 + r))*4096 + l0 + q*16;
    #pragma unroll
    for (int j = 0; j < 4; ++j){
      const f32x4 v = *reinterpret_cast<const f32x4*>(src + j*4);
      #pragma unroll
      for (int e = 0; e < 4; ++e) tile[r][q*16 + j*4 + e] = v[e];
    }
  }
  __syncthreads();
  {
    const int jr = tid >> 2, cq = tid & 3;
    unsigned int w[8];
    #pragma unroll
    for (int e = 0; e < 8; ++e){
      const float lo = tile[cq*16 + 2*e][jr];
      const float hi = tile[cq*16 + 2*e + 1][jr];
      w[e] = (unsigned int)f2b(lo) | ((unsigned int)f2b(hi) << 16);
    }
    unsigned short* dst = (unsigned short*)xt + ((size_t)b*4098 + l0 + jr + 1)*256 + c0 + cq*16;
    uint4v a0 = {w[0],w[1],w[2],w[3]}, a1 = {w[4],w[5],w[6],w[7]};
    *reinterpret_cast<uint4v*>(dst)     = a0;
    *reinterpret_cast<uint4v*>(dst + 8) = a1;
  }
}

// ---- zero pad rows (lp=0 and lp=4097) of xT and h1T ----
__global__ void k_zero_pads(bf16* __restrict__ xt, bf16* __restrict__ h1t)
{
  const int b = blockIdx.x, tid = threadIdx.x;
  const size_t top = (size_t)b*4098*256 + tid;
  const size_t bot = (size_t)b*4098*256 + (size_t)4097*256 + tid;
  unsigned short* px = (unsigned short*)xt;
  unsigned short* ph = (unsigned short*)h1t;
  px[top] = 0; px[bot] = 0; ph[top] = 0; ph[bot] = 0;
}

// ---- f32 -> bf16 convert for 3 equally-sized tensors packed into dst ----
__global__ __launch_bounds__(256) void k_cvt3(const float* __restrict__ s0, const float* __restrict__ s1,
                                              const float* __restrict__ s2, bf16* __restrict__ dst, int n1)
{
  const size_t total = (size_t)3 * (size_t)n1 / 4;
  for (size_t i = (size_t)blockIdx.x*256 + threadIdx.x; i < total; i += (size_t)gridDim.x*256){
    const size_t e = i*4;
    const int which = (int)(e / (size_t)n1);
    const size_t off = e - (size_t)which*(size_t)n1;
    const float* s = which==0 ? s0 : which==1 ? s1 : s2;
    const f32x4 v = *reinterpret_cast<const f32x4*>(s + off);
    uint2v p;
    p[0] = (unsigned)f2b(v[0]) | ((unsigned)f2b(v[1])<<16);
    p[1] = (unsigned)f2b(v[2]) | ((unsigned)f2b(v[3])<<16);
    *reinterpret_cast<uint2v*>((unsigned short*)dst + e) = p;
  }
}

// ============================================================================
// Pipelined 256x256 GEMM template pieces (T3+T4: dbuf LDS + counted vmcnt).
// 512 threads = 8 waves (2 M x 4 N); per-wave 128x64 out; BK=64.
// LDS: sA[2][256*64], sB[2][256*64] = 128 KiB. Swizzle: 16B slot ^ (row&7),
// applied to pre-swizzled global source (gload_lds dest stays linear) and read.
// Per K-step: STAGE(next->buf^1)[8 loads]; vmcnt(8); barrier; ds+MFMA; barrier.
// ============================================================================

// ---- hypernet weight gen: Wt[i][bb][t][o][c] = sum_h wb_i[c*3+t][h]*attb_i[bo][h] + bias
__global__ __launch_bounds__(512, 2) void k_gen(const bf16* __restrict__ attb, const bf16* __restrict__ wbp,
                                                const float* __restrict__ bias0, const float* __restrict__ bias1,
                                                const float* __restrict__ bias2, bf16* __restrict__ Wt)
{
  __shared__ bf16 sA[2][256*64];
  __shared__ bf16 sB[2][256*64];
  const int iz = blockIdx.z, i = iz/3, t = iz - i*3;
  const int bo0 = blockIdx.x*256;
  const bf16* __restrict__ A  = wbp  + (size_t)i*768*1024 + (size_t)t*1024;
  const bf16* __restrict__ Bt = attb + (size_t)i*4096*1024 + (size_t)bo0*1024;
  const float* __restrict__ bias = (i==0) ? bias0 : (i==1) ? bias1 : bias2;
  const int tid = threadIdx.x, lane = tid & 63, wid = tid >> 6;
  const int wr = wid >> 2, wc = wid & 3;
  const int frow = lane & 15, g = lane >> 4;
  f32x4 acc[8][4] = {};

#define GEN_STAGE(kt, bufi) { \
    const int kc = (kt)*64; \
    _Pragma("unroll") \
    for (int j = 0; j < 4; ++j){ \
      const int slot = tid + j*512, r = slot >> 3, s7 = slot & 7; \
      const int cc = (s7 ^ (r & 7)) * 8; \
      gload16(A + (size_t)r*3072 + kc + cc, &sA[bufi][slot*8]); \
    } \
    _Pragma("unroll") \
    for (int j = 0; j < 4; ++j){ \
      const int slot = tid + j*512, r = slot >> 3, s7 = slot & 7; \
      const int cc = (s7 ^ (r & 7)) * 8; \
      gload16(Bt + (size_t)r*1024 + kc + cc, &sB[bufi][slot*8]); \
    } \
  }

  GEN_STAGE(0, 0);
  #pragma unroll 1
  for (int kt = 0; kt < 16; ++kt){
    const int buf = kt & 1;
    if (kt + 1 < 16){
      GEN_STAGE(kt+1, buf^1);
      asm volatile("s_waitcnt vmcnt(8)" ::: "memory");
    } else {
      asm volatile("s_waitcnt vmcnt(0)" ::: "memory");
    }
    __builtin_amdgcn_s_barrier();
    __builtin_amdgcn_sched_barrier(0);
    const bf16* pA = sA[buf];
    const bf16* pB = sB[buf];
    #pragma unroll
    for (int ks = 0; ks < 2; ++ks){
      short8 bfr[4];
      #pragma unroll
      for (int n = 0; n < 4; ++n){
        const int row = wc*64 + n*16 + frow;
        const int sl = (ks*4 + g) ^ (row & 7);
        bfr[n] = *reinterpret_cast<const short8*>(pB + row*64 + sl*8);
      }
      __builtin_amdgcn_s_setprio(1);
      #pragma unroll
      for (int m = 0; m < 8; ++m){
        const int row = wr*128 + m*16 + frow;
        const int sl = (ks*4 + g) ^ (row & 7);
        const short8 af = *reinterpret_cast<const short8*>(pA + row*64 + sl*8);
        #pragma unroll
        for (int n = 0; n < 4; ++n)
          acc[m][n] = __builtin_amdgcn_mfma_f32_16x16x32_bf16(af, bfr[n], acc[m][n], 0, 0, 0);
      }
      __builtin_amdgcn_s_setprio(0);
    }
    __builtin_amdgcn_sched_barrier(0);
    __builtin_amdgcn_s_barrier();
    __builtin_amdgcn_sched_barrier(0);
  }
#undef GEN_STAGE

  #pragma unroll
  for (int m = 0; m < 8; ++m){
    const int cb = wr*128 + m*16 + g*4;
    float bi[4];
    #pragma unroll
    for (int j = 0; j < 4; ++j) bi[j] = bias[(cb + j)*3 + t];
    #pragma unroll
    for (int n = 0; n < 4; ++n){
      const int bo = bo0 + wc*64 + n*16 + frow;
      const int bb = bo >> 8, o = bo & 255;
      unsigned short* dst = (unsigned short*)Wt + ((((size_t)(i*16 + bb)*3 + t)*256 + o)*256 + cb);
      uint2v p;
      p[0] = (unsigned)f2b(acc[m][n][0] + bi[0]) | ((unsigned)f2b(acc[m][n][1] + bi[1]) << 16);
      p[1] = (unsigned)f2b(acc[m][n][2] + bi[2]) | ((unsigned)f2b(acc[m][n][3] + bi[3]) << 16);
      *reinterpret_cast<uint2v*>(dst) = p;
    }
  }
}

// ---- b1[b*256+o] = att1[bo,:] . b1_w + b1_b ----
__global__ __launch_bounds__(256) void k_b1(const float* __restrict__ att1, const float* __restrict__ b1w,
                                            const float* __restrict__ b1b, float* __restrict__ out)
{
  const int m = blockIdx.x*4 + (threadIdx.x >> 6);
  const int lane = threadIdx.x & 63;
  const float* a = att1 + (size_t)m*1024;
  float s = 0.f;
  for (int k = lane*4; k < 1024; k += 256){
    const f32x4 v = *reinterpret_cast<const f32x4*>(a + k);
    const f32x4 w = *reinterpret_cast<const f32x4*>(b1w + k);
    s += v[0]*w[0] + v[1]*w[1] + v[2]*w[2] + v[3]*w[3];
  }
  #pragma unroll
  for (int d = 32; d > 0; d >>= 1) s += __shfl_down(s, d);
  if (lane == 0) out[m] = s + b1b[0];
}

// ---- att_conv: out[b][l][o](+rowOff) = sum_t sum_c W[b][t][o][c] * Xt[b][l+t][c]
// K = 768 (12 tiles of 64: tap t = kt>>2, c0 = (kt&3)*64). M=256 (o), N=256 (l)/tile.
__global__ __launch_bounds__(512, 2) void k_conv(const bf16* __restrict__ Xt, const bf16* __restrict__ W,
                                                 const float* __restrict__ bias, bf16* __restrict__ out,
                                                 int outBatchStride, int outRowOff, int applyRelu,
                                                 float* __restrict__ statSum, float* __restrict__ statSq)
{
  __shared__ bf16 sA[2][256*64];
  __shared__ bf16 sB[2][256*64];
  const int b = blockIdx.z, l0 = blockIdx.x*256;
  const int tid = threadIdx.x, lane = tid & 63, wid = tid >> 6;
  const int wr = wid >> 2, wc = wid & 3;
  const int frow = lane & 15, g = lane >> 4;
  f32x4 acc[8][4] = {};

#define CONV_STAGE(kt, bufi) { \
    const int tt = (kt) >> 2, c0 = ((kt) & 3)*64; \
    const bf16* Ab = W  + (((size_t)b*3 + tt)*256)*256 + c0; \
    const bf16* Bb = Xt + ((size_t)b*4098 + l0 + tt)*256 + c0; \
    _Pragma("unroll") \
    for (int j = 0; j < 4; ++j){ \
      const int slot = tid + j*512, r = slot >> 3, s7 = slot & 7; \
      const int cc = (s7 ^ (r & 7)) * 8; \
      gload16(Ab + (size_t)r*256 + cc, &sA[bufi][slot*8]); \
    } \
    _Pragma("unroll") \
    for (int j = 0; j < 4; ++j){ \
      const int slot = tid + j*512, r = slot >> 3, s7 = slot & 7; \
      const int cc = (s7 ^ (r & 7)) * 8; \
      gload16(Bb + (size_t)r*256 + cc, &sB[bufi][slot*8]); \
    } \
  }

  CONV_STAGE(0, 0);
  #pragma unroll 1
  for (int kt = 0; kt < 12; ++kt){
    const int buf = kt & 1;
    if (kt + 1 < 12){
      CONV_STAGE(kt+1, buf^1);
      asm volatile("s_waitcnt vmcnt(8)" ::: "memory");
    } else {
      asm volatile("s_waitcnt vmcnt(0)" ::: "memory");
    }
    __builtin_amdgcn_s_barrier();
    __builtin_amdgcn_sched_barrier(0);
    const bf16* pA = sA[buf];
    const bf16* pB = sB[buf];
    #pragma unroll
    for (int ks = 0; ks < 2; ++ks){
      short8 bfr[4];
      #pragma unroll
      for (int n = 0; n < 4; ++n){
        const int row = wc*64 + n*16 + frow;
        const int sl = (ks*4 + g) ^ (row & 7);
        bfr[n] = *reinterpret_cast<const short8*>(pB + row*64 + sl*8);
      }
      __builtin_amdgcn_s_setprio(1);
      #pragma unroll
      for (int m = 0; m < 8; ++m){
        const int row = wr*128 + m*16 + frow;
        const int sl = (ks*4 + g) ^ (row & 7);
        const short8 af = *reinterpret_cast<const short8*>(pA + row*64 + sl*8);
        #pragma unroll
        for (int n = 0; n < 4; ++n)
          acc[m][n] = __builtin_amdgcn_mfma_f32_16x16x32_bf16(af, bfr[n], acc[m][n], 0, 0, 0);
      }
      __builtin_amdgcn_s_setprio(0);
    }
    __builtin_amdgcn_sched_barrier(0);
    __builtin_amdgcn_s_barrier();
    __builtin_amdgcn_sched_barrier(0);
  }
#undef CONV_STAGE

  float cs[8][4] = {{0.f}}, cq[8][4] = {{0.f}};
  #pragma unroll
  for (int m = 0; m < 8; ++m){
    const int ob = wr*128 + m*16 + g*4;
    float bi[4] = {0.f, 0.f, 0.f, 0.f};
    if (bias){
      const f32x4 bv = *reinterpret_cast<const f32x4*>(bias + b*256 + ob);
      bi[0]=bv[0]; bi[1]=bv[1]; bi[2]=bv[2]; bi[3]=bv[3];
    }
    #pragma unroll
    for (int n = 0; n < 4; ++n){
      const int l = l0 + wc*64 + n*16 + frow;
      float v[4];
      #pragma unroll
      for (int j = 0; j < 4; ++j){
        v[j] = acc[m][n][j] + bi[j];
        if (applyRelu) v[j] = fmaxf(v[j], 0.f);
        cs[m][j] += v[j];
        cq[m][j] += v[j]*v[j];
      }
      unsigned short* dst = (unsigned short*)out +
          ((size_t)b*outBatchStride + (size_t)(l + outRowOff)*256 + ob);
      uint2v p;
      p[0] = (unsigned)f2b(v[0]) | ((unsigned)f2b(v[1]) << 16);
      p[1] = (unsigned)f2b(v[2]) | ((unsigned)f2b(v[3]) << 16);
      *reinterpret_cast<uint2v*>(dst) = p;
    }
  }
  if (statSum){
    #pragma unroll
    for (int m = 0; m < 8; ++m)
      #pragma unroll
      for (int j = 0; j < 4; ++j){
        #pragma unroll
        for (int d = 1; d < 16; d <<= 1){
          cs[m][j] += __shfl_xor(cs[m][j], d);
          cq[m][j] += __shfl_xor(cq[m][j], d);
        }
      }
    __syncthreads();
    float* ls = (float*)&sA[0][0];     // [8 waves][128 ch]
    float* lq = ls + 1024;
    if (frow == 0){
      #pragma unroll
      for (int m = 0; m < 8; ++m)
        #pragma unroll
        for (int j = 0; j < 4; ++j){
          ls[wid*128 + m*16 + g*4 + j] = cs[m][j];
          lq[wid*128 + m*16 + g*4 + j] = cq[m][j];
        }
    }
    __syncthreads();
    if (tid < 256){
      const int o = tid, half = o >> 7, idx = o & 127;
      float s = 0.f, qq = 0.f;
      #pragma unroll
      for (int wv = 0; wv < 4; ++wv){
        s  += ls[(half*4 + wv)*128 + idx];
        qq += lq[(half*4 + wv)*128 + idx];
      }
      atomicAdd(statSum + o, s);
      atomicAdd(statSq  + o, qq);
    }
  }
}

__global__ void k_bnfin(const float* __restrict__ sum, const float* __restrict__ sq,
                        const float* __restrict__ g, const float* __restrict__ bb,
                        float* __restrict__ scale, float* __restrict__ shift)
{
  const int o = threadIdx.x;
  const float inv = 1.f/65536.f;
  const float m = sum[o]*inv;
  const float v = fmaxf(sq[o]*inv - m*m, 0.f);
  const float sc = g[o] / sqrtf(v + 1e-5f);
  scale[o] = sc;
  shift[o] = bb[o] - m*sc;
}

// ---- h2T[b][lp][o] = relu(y2T[b][lp-1][o]*scale+shift), pads zeroed ----
__global__ __launch_bounds__(256) void k_norm2(const bf16* __restrict__ y, const float* __restrict__ scale,
                                               const float* __restrict__ shift, bf16* __restrict__ h)
{
  const int gr = blockIdx.x*8 + (threadIdx.x >> 5);
  const int oc = threadIdx.x & 31;
  const int b = gr / 4098, lp = gr - b*4098;
  unsigned short* dst = (unsigned short*)h + (size_t)gr*256 + oc*8;
  if (lp == 0 || lp == 4097){
    uint4v z = {0u,0u,0u,0u};
    *reinterpret_cast<uint4v*>(dst) = z;
    return;
  }
  const unsigned short* src = (const unsigned short*)y + ((size_t)b*4096 + (lp-1))*256 + oc*8;
  const uint4v in = *reinterpret_cast<const uint4v*>(src);
  const f32x4 sA0 = *reinterpret_cast<const f32x4*>(scale + oc*8);
  const f32x4 sA1 = *reinterpret_cast<const f32x4*>(scale + oc*8 + 4);
  const f32x4 hA0 = *reinterpret_cast<const f32x4*>(shift + oc*8);
  const f32x4 hA1 = *reinterpret_cast<const f32x4*>(shift + oc*8 + 4);
  uint4v ov;
  #pragma unroll
  for (int e = 0; e < 4; ++e){
    const unsigned int w = in[e];
    const float sc0 = (e<2) ? sA0[2*e] : sA1[2*e-4];
    const float sc1 = (e<2) ? sA0[2*e+1] : sA1[2*e-3];
    const float sh0 = (e<2) ? hA0[2*e] : hA1[2*e-4];
    const float sh1 = (e<2) ? hA0[2*e+1] : hA1[2*e-3];
    const float v0 = fmaxf(b2f((unsigned short)(w & 0xffffu))*sc0 + sh0, 0.f);
    const float v1 = fmaxf(b2f((unsigned short)(w >> 16))*sc1 + sh1, 0.f);
    ov[e] = (unsigned)f2b(v0) | ((unsigned)f2b(v1) << 16);
  }
  *reinterpret_cast<uint4v*>(dst) = ov;
}

// ---- h3 = relu(y3*scale+shift) in-place, plus per-(b,o) sums for SE ----
__global__ __launch_bounds__(256) void k_norm3(bf16* __restrict__ y, const float* __restrict__ scale,
                                               const float* __restrict__ shift, float* __restrict__ s_sum)
{
  __shared__ float red[8][256];
  const int tid = threadIdx.x;
  const int rr = tid >> 5, oc = tid & 31;
  const size_t row = (size_t)blockIdx.x*8 + rr;
  const int b = (int)(row >> 12);
  unsigned short* p = (unsigned short*)y + row*256 + oc*8;
  const uint4v in = *reinterpret_cast<const uint4v*>(p);
  const f32x4 sA0 = *reinterpret_cast<const f32x4*>(scale + oc*8);
  const f32x4 sA1 = *reinterpret_cast<const f32x4*>(scale + oc*8 + 4);
  const f32x4 hA0 = *reinterpret_cast<const f32x4*>(shift + oc*8);
  const f32x4 hA1 = *reinterpret_cast<const f32x4*>(shift + oc*8 + 4);
  uint4v ov;
  float loc[8];
  #pragma unroll
  for (int e = 0; e < 4; ++e){
    const unsigned int w = in[e];
    const float sc0 = (e<2) ? sA0[2*e] : sA1[2*e-4];
    const float sc1 = (e<2) ? sA0[2*e+1] : sA1[2*e-3];
    const float sh0 = (e<2) ? hA0[2*e] : hA1[2*e-4];
    const float sh1 = (e<2) ? hA0[2*e+1] : hA1[2*e-3];
    const float v0 = fmaxf(b2f((unsigned short)(w & 0xffffu))*sc0 + sh0, 0.f);
    const float v1 = fmaxf(b2f((unsigned short)(w >> 16))*sc1 + sh1, 0.f);
    loc[2*e] = v0; loc[2*e+1] = v1;
    ov[e] = (unsigned)f2b(v0) | ((unsigned)f2b(v1) << 16);
  }
  *reinterpret_cast<uint4v*>(p) = ov;
  #pragma unroll
  for (int j = 0; j < 8; ++j) red[rr][oc*8 + j] = loc[j];
  __syncthreads();
  const int o = tid;
  float tot = 0.f;
  #pragma unroll
  for (int r2 = 0; r2 < 8; ++r2) tot += red[r2][o];
  atomicAdd(&s_sum[(size_t)b*256 + o], tot);
}

// ---- SE: s2[b][o] = sigmoid(W2 @ relu(W1 @ mean + b1) + b2) ----
__global__ __launch_bounds__(256) void k_se(const float* __restrict__ s_sum, const float* __restrict__ w1,
                                            const float* __restrict__ b1, const float* __restrict__ w2,
                                            const float* __restrict__ b2, float* __restrict__ s2)
{
  __shared__ float sv[256];
  __shared__ float t1[256];
  const int b = blockIdx.x, o = threadIdx.x;
  sv[o] = s_sum[(size_t)b*256 + o] * (1.f/4096.f);
  __syncthreads();
  float a = b1[o];
  for (int c = 0; c < 256; ++c) a += w1[(size_t)o*256 + c] * sv[c];
  t1[o] = fmaxf(a, 0.f);
  __syncthreads();
  float a2 = b2[o];
  for (int c = 0; c < 256; ++c) a2 += w2[(size_t)o*256 + c] * t1[c];
  s2[(size_t)b*256 + o] = 1.f / (1.f + expf(-a2));
}

// ---- out[b][o][l] = relu(h3T[b][l][o]*s2[b][o] + x[b][o][l]) ----
__global__ __launch_bounds__(256) void k_final(const bf16* __restrict__ h3, const float* __restrict__ s2,
                                               const float* __restrict__ x, float* __restrict__ out)
{
  __shared__ float tile[64][65];
  const int b = blockIdx.z, o0 = blockIdx.y*64, l0 = blockIdx.x*64;
  const int tid = threadIdx.x;
  {
    const int r = tid >> 2, q = tid & 3;
    const unsigned short* src = (const unsigned short*)h3 + ((size_t)b*4096 + l0 + r)*256 + o0 + q*16;
    const uint4v a0 = *reinterpret_cast<const uint4v*>(src);
    const uint4v a1 = *reinterpret_cast<const uint4v*>(src + 8);
    #pragma unroll
    for (int e = 0; e < 4; ++e){
      tile[r][q*16 + 2*e]         = b2f((unsigned short)(a0[e] & 0xffffu));
      tile[r][q*16 + 2*e + 1]     = b2f((unsigned short)(a0[e] >> 16));
      tile[r][q*16 + 8 + 2*e]     = b2f((unsigned short)(a1[e] & 0xffffu));
      tile[r][q*16 + 8 + 2*e + 1] = b2f((unsigned short)(a1[e] >> 16));
    }
  }
  __syncthreads();
  {
    const int orow = tid >> 2, q = tid & 3;
    const int o = o0 + orow;
    const float sc = s2[(size_t)b*256 + o];
    const float* xs = x + ((size_t)b*256 + o)*4096 + l0 + q*16;
    float* dst = out + ((size_t)b*256 + o)*4096 + l0 + q*16;
    #pragma unroll
    for (int k = 0; k < 16; k += 4){
      const f32x4 xv = *reinterpret_cast<const f32x4*>(xs + k);
      f32x4 r;
      #pragma unroll
      for (int e = 0; e < 4; ++e)
        r[e] = fmaxf(tile[q*16 + k + e][orow]*sc + xv[e], 0.f);
      *reinterpret_cast<f32x4*>(dst + k) = r;
    }
  }
}

extern "C" void kernel_launch(void* const* d_in, const int* in_sizes, int n_in,
                              void* d_out, int out_size, void* d_ws, size_t ws_size,
                              hipStream_t stream)
{
  const float* x     = (const float*)d_in[0];
  const float* att1  = (const float*)d_in[1];
  const float* att2  = (const float*)d_in[2];
  const float* att3  = (const float*)d_in[3];
  const float* w1_w  = (const float*)d_in[4];
  const float* w1_b  = (const float*)d_in[5];
  const float* w2_w  = (const float*)d_in[6];
  const float* w2_b  = (const float*)d_in[7];
  const float* w3_w  = (const float*)d_in[8];
  const float* w3_b  = (const float*)d_in[9];
  const float* b1_w  = (const float*)d_in[10];
  const float* b1_b  = (const float*)d_in[11];
  const float* bn2_w = (const float*)d_in[12];
  const float* bn2_b = (const float*)d_in[13];
  const float* bn3_w = (const float*)d_in[14];
  const float* bn3_b = (const float*)d_in[15];
  const float* se1_w = (const float*)d_in[16];
  const float* se1_b = (const float*)d_in[17];
  const float* se2_w = (const float*)d_in[18];
  const float* se2_b = (const float*)d_in[19];

  char* ws = (char*)d_ws;
  // workspace layout (bytes)
  bf16*  xT   = (bf16*)(ws + 0);           // [16][4098][256]  (reused as y3T/h3T)
  bf16*  h1T  = (bf16*)(ws + 33570816);    // [16][4098][256]
  bf16*  y2T  = (bf16*)(ws + 67141632);    // [16][4096][256]
  bf16*  h2T  = (bf16*)(ws + 100696064);   // [16][4098][256]
  bf16*  Wt   = (bf16*)(ws + 134266880);   // [3][16][3][256][256]
  bf16*  attb = (bf16*)(ws + 153141248);   // [3][4096][1024]
  bf16*  wb   = (bf16*)(ws + 178307072);   // [3][768][1024]
  float* b1v  = (float*)(ws + 183025664);  // [4096]
  float* st   = (float*)(ws + 183042048);
  float* bn2sum = st;          // 256
  float* bn2sq  = st + 256;
  float* bn3sum = st + 512;
  float* bn3sq  = st + 768;
  float* s_sum  = st + 1024;   // 4096
  float* scale2 = st + 5120;
  float* shift2 = st + 5376;
  float* scale3 = st + 5632;
  float* shift3 = st + 5888;
  float* s2v    = st + 6144;   // 4096
  bf16*  y3T  = (bf16*)(ws + 0);           // overlay on xT (dead after conv1)

  // zero accumulators (bn2/bn3 sums + s_sum = 5120 floats)
  hipMemsetAsync(st, 0, 5120*sizeof(float), stream);

  k_transpose_x<<<dim3(64,4,16),256,0,stream>>>(x, xT);
  k_zero_pads<<<16,256,0,stream>>>(xT, h1T);
  k_cvt3<<<2048,256,0,stream>>>(att1, att2, att3, attb, 4096*1024);
  k_cvt3<<<512,256,0,stream>>>(w1_w, w2_w, w3_w, wb, 768*1024);
  k_gen<<<dim3(16,1,9),512,0,stream>>>(attb, wb, w1_b, w2_b, w3_b, Wt);
  k_b1<<<1024,256,0,stream>>>(att1, b1_w, b1_b, b1v);

  k_conv<<<dim3(16,1,16),512,0,stream>>>(xT,  Wt,                           b1v,     h1T, 4098*256, 1, 1, nullptr, nullptr);
  k_conv<<<dim3(16,1,16),512,0,stream>>>(h1T, Wt + (size_t)1*16*3*256*256,  nullptr, y2T, 4096*256, 0, 0, bn2sum, bn2sq);
  k_bnfin<<<1,256,0,stream>>>(bn2sum, bn2sq, bn2_w, bn2_b, scale2, shift2);
  k_norm2<<<8196,256,0,stream>>>(y2T, scale2, shift2, h2T);
  k_conv<<<dim3(16,1,16),512,0,stream>>>(h2T, Wt + (size_t)2*16*3*256*256,  nullptr, y3T, 4096*256, 0, 0, bn3sum, bn3sq);
  k_bnfin<<<1,256,0,stream>>>(bn3sum, bn3sq, bn3_w, bn3_b, scale3, shift3);
  k_norm3<<<8192,256,0,stream>>>(y3T, scale3, shift3, s_sum);
  k_se<<<16,256,0,stream>>>(s_sum, se1_w, se1_b, se2_w, se2_b, s2v);
  k_final<<<dim3(64,4,16),256,0,stream>>>((const bf16*)y3T, s2v, x, (float*)d_out);
}

// Round 4
// 307.768 us; speedup vs baseline: 1.1799x; 1.1038x over previous
//
#include <hip/hip_runtime.h>
#include <hip/hip_bf16.h>

using bf16 = __hip_bfloat16;
typedef __attribute__((ext_vector_type(4))) float f32x4;
typedef __attribute__((ext_vector_type(8))) short short8;
typedef __attribute__((ext_vector_type(2))) unsigned int uint2v;
typedef __attribute__((ext_vector_type(4))) unsigned int uint4v;

#define DEVI static __device__ __forceinline__

DEVI unsigned short f2b(float f){
  unsigned int u = __float_as_uint(f);
  unsigned int r = (u + 0x7fffu + ((u >> 16) & 1u)) >> 16;
  return (unsigned short)r;
}
DEVI float b2f(unsigned short u){
  return __uint_as_float(((unsigned int)u) << 16);
}

DEVI void gload16(const void* g, void* l){
  __builtin_amdgcn_global_load_lds(
      (const __attribute__((address_space(1))) unsigned int*)g,
      (__attribute__((address_space(3))) unsigned int*)l, 16, 0, 0);
}

// ---- x [16][256][4096] f32 -> xT [16][4098][256] bf16 (row lp = l+1) ----
__global__ __launch_bounds__(256) void k_transpose_x(const float* __restrict__ x,
                                                     bf16* __restrict__ xt)
{
  __shared__ float tile[64][65];
  const int b = blockIdx.z, l0 = blockIdx.x*64, c0 = blockIdx.y*64;
  const int tid = threadIdx.x;
  {
    const int r = tid >> 2, q = tid & 3;
    const float* src = x + ((size_t)(b*256 + c0 + r))*4096 + l0 + q*16;
    #pragma unroll
    for (int j = 0; j < 4; ++j){
      const f32x4 v = *reinterpret_cast<const f32x4*>(src + j*4);
      #pragma unroll
      for (int e = 0; e < 4; ++e) tile[r][q*16 + j*4 + e] = v[e];
    }
  }
  __syncthreads();
  {
    const int jr = tid >> 2, cq = tid & 3;
    unsigned int w[8];
    #pragma unroll
    for (int e = 0; e < 8; ++e){
      const float lo = tile[cq*16 + 2*e][jr];
      const float hi = tile[cq*16 + 2*e + 1][jr];
      w[e] = (unsigned int)f2b(lo) | ((unsigned int)f2b(hi) << 16);
    }
    unsigned short* dst = (unsigned short*)xt + ((size_t)b*4098 + l0 + jr + 1)*256 + c0 + cq*16;
    uint4v a0 = {w[0],w[1],w[2],w[3]}, a1 = {w[4],w[5],w[6],w[7]};
    *reinterpret_cast<uint4v*>(dst)     = a0;
    *reinterpret_cast<uint4v*>(dst + 8) = a1;
  }
}

// ---- zero pad rows (lp=0 and lp=4097) of xT and h1T ----
__global__ void k_zero_pads(bf16* __restrict__ xt, bf16* __restrict__ h1t)
{
  const int b = blockIdx.x, tid = threadIdx.x;
  const size_t top = (size_t)b*4098*256 + tid;
  const size_t bot = (size_t)b*4098*256 + (size_t)4097*256 + tid;
  unsigned short* px = (unsigned short*)xt;
  unsigned short* ph = (unsigned short*)h1t;
  px[top] = 0; px[bot] = 0; ph[top] = 0; ph[bot] = 0;
}

// ---- f32 -> bf16 convert for 3 equally-sized tensors packed into dst ----
__global__ __launch_bounds__(256) void k_cvt3(const float* __restrict__ s0, const float* __restrict__ s1,
                                              const float* __restrict__ s2, bf16* __restrict__ dst, int n1)
{
  const size_t total = (size_t)3 * (size_t)n1 / 4;
  for (size_t i = (size_t)blockIdx.x*256 + threadIdx.x; i < total; i += (size_t)gridDim.x*256){
    const size_t e = i*4;
    const int which = (int)(e / (size_t)n1);
    const size_t off = e - (size_t)which*(size_t)n1;
    const float* s = which==0 ? s0 : which==1 ? s1 : s2;
    const f32x4 v = *reinterpret_cast<const f32x4*>(s + off);
    uint2v p;
    p[0] = (unsigned)f2b(v[0]) | ((unsigned)f2b(v[1])<<16);
    p[1] = (unsigned)f2b(v[2]) | ((unsigned)f2b(v[3])<<16);
    *reinterpret_cast<uint2v*>((unsigned short*)dst + e) = p;
  }
}

// ============================================================================
// Pipelined 256x256 GEMM (T3+T4: dbuf LDS + counted vmcnt), 512 thr = 8 waves
// (2M x 4N), per-wave 128x64 out, BK=64. LDS 131072 B shared between the
// staging double-buffers (4 x 16384 bf16) and the epilogue C-tile (256x256).
// Staging swizzle: 16B slot ^ (row&7) on pre-swizzled global source.
// Epilogue: acc -> LDS C-tile (16B-chunk ^ (row&31) swizzle) -> full-line
// 512 B/row coalesced global stores (kills L2 write-allocate refetch).
// ============================================================================

// ---- hypernet weight gen: Wt[i][bx][t][o][c] = sum_h wb_i[c*3+t][h]*attb_i[bo][h] + bias
__global__ __launch_bounds__(512, 2) void k_gen(const bf16* __restrict__ attb, const bf16* __restrict__ wbp,
                                                const float* __restrict__ bias0, const float* __restrict__ bias1,
                                                const float* __restrict__ bias2, bf16* __restrict__ Wt)
{
  __shared__ bf16 sAll[4*16384];
  const int iz = blockIdx.z, i = iz/3, t = iz - i*3;
  const int bx = blockIdx.x, bo0 = bx*256;
  const bf16* __restrict__ A  = wbp  + (size_t)i*768*1024 + (size_t)t*1024;
  const bf16* __restrict__ Bt = attb + (size_t)i*4096*1024 + (size_t)bo0*1024;
  const float* __restrict__ bias = (i==0) ? bias0 : (i==1) ? bias1 : bias2;
  const int tid = threadIdx.x, lane = tid & 63, wid = tid >> 6;
  const int wr = wid >> 2, wc = wid & 3;
  const int frow = lane & 15, g = lane >> 4;
  f32x4 acc[8][4] = {};

#define GEN_STAGE(kt, bufi) { \
    const int kc = (kt)*64; \
    _Pragma("unroll") \
    for (int j = 0; j < 4; ++j){ \
      const int slot = tid + j*512, r = slot >> 3, s7 = slot & 7; \
      const int cc = (s7 ^ (r & 7)) * 8; \
      gload16(A + (size_t)r*3072 + kc + cc, &sAll[(bufi)*16384 + slot*8]); \
    } \
    _Pragma("unroll") \
    for (int j = 0; j < 4; ++j){ \
      const int slot = tid + j*512, r = slot >> 3, s7 = slot & 7; \
      const int cc = (s7 ^ (r & 7)) * 8; \
      gload16(Bt + (size_t)r*1024 + kc + cc, &sAll[32768 + (bufi)*16384 + slot*8]); \
    } \
  }

  GEN_STAGE(0, 0);
  #pragma unroll 1
  for (int kt = 0; kt < 16; ++kt){
    const int buf = kt & 1;
    if (kt + 1 < 16){
      GEN_STAGE(kt+1, buf^1);
      asm volatile("s_waitcnt vmcnt(8)" ::: "memory");
    } else {
      asm volatile("s_waitcnt vmcnt(0)" ::: "memory");
    }
    __builtin_amdgcn_s_barrier();
    __builtin_amdgcn_sched_barrier(0);
    const bf16* pA = sAll + buf*16384;
    const bf16* pB = sAll + 32768 + buf*16384;
    #pragma unroll
    for (int ks = 0; ks < 2; ++ks){
      short8 bfr[4];
      #pragma unroll
      for (int n = 0; n < 4; ++n){
        const int row = wc*64 + n*16 + frow;
        const int sl = (ks*4 + g) ^ (row & 7);
        bfr[n] = *reinterpret_cast<const short8*>(pB + row*64 + sl*8);
      }
      __builtin_amdgcn_s_setprio(1);
      #pragma unroll
      for (int m = 0; m < 8; ++m){
        const int row = wr*128 + m*16 + frow;
        const int sl = (ks*4 + g) ^ (row & 7);
        const short8 af = *reinterpret_cast<const short8*>(pA + row*64 + sl*8);
        #pragma unroll
        for (int n = 0; n < 4; ++n)
          acc[m][n] = __builtin_amdgcn_mfma_f32_16x16x32_bf16(af, bfr[n], acc[m][n], 0, 0, 0);
      }
      __builtin_amdgcn_s_setprio(0);
    }
    __builtin_amdgcn_sched_barrier(0);
    __builtin_amdgcn_s_barrier();
    __builtin_amdgcn_sched_barrier(0);
  }
#undef GEN_STAGE

  // epilogue: acc -> swizzled LDS C-tile [256 o][256 c], then full-line blast
  #pragma unroll
  for (int m = 0; m < 8; ++m){
    const int col = wr*128 + m*16 + g*4;
    float bi[4];
    #pragma unroll
    for (int j = 0; j < 4; ++j) bi[j] = bias[(col + j)*3 + t];
    #pragma unroll
    for (int n = 0; n < 4; ++n){
      const int row = wc*64 + n*16 + frow;
      uint2v p;
      p[0] = (unsigned)f2b(acc[m][n][0] + bi[0]) | ((unsigned)f2b(acc[m][n][1] + bi[1]) << 16);
      p[1] = (unsigned)f2b(acc[m][n][2] + bi[2]) | ((unsigned)f2b(acc[m][n][3] + bi[3]) << 16);
      const int chunk = (col >> 3) ^ (row & 31);
      *reinterpret_cast<uint2v*>((char*)sAll + row*512 + chunk*16 + (g&1)*8) = p;
    }
  }
  __syncthreads();
  {
    char* gp = (char*)Wt + 2*(((size_t)(i*16 + bx)*3 + t)*65536);
    #pragma unroll
    for (int p2 = 0; p2 < 16; ++p2){
      const int row = p2*16 + (tid >> 5);
      const int c = tid & 31;
      const int cs2 = c ^ (row & 31);
      const uint4v v = *reinterpret_cast<const uint4v*>((const char*)sAll + row*512 + cs2*16);
      *reinterpret_cast<uint4v*>(gp + (size_t)row*512 + c*16) = v;
    }
  }
}

// ---- b1[b*256+o] = att1[bo,:] . b1_w + b1_b ----
__global__ __launch_bounds__(256) void k_b1(const float* __restrict__ att1, const float* __restrict__ b1w,
                                            const float* __restrict__ b1b, float* __restrict__ out)
{
  const int m = blockIdx.x*4 + (threadIdx.x >> 6);
  const int lane = threadIdx.x & 63;
  const float* a = att1 + (size_t)m*1024;
  float s = 0.f;
  for (int k = lane*4; k < 1024; k += 256){
    const f32x4 v = *reinterpret_cast<const f32x4*>(a + k);
    const f32x4 w = *reinterpret_cast<const f32x4*>(b1w + k);
    s += v[0]*w[0] + v[1]*w[1] + v[2]*w[2] + v[3]*w[3];
  }
  #pragma unroll
  for (int d = 32; d > 0; d >>= 1) s += __shfl_down(s, d);
  if (lane == 0) out[m] = s + b1b[0];
}

// ---- att_conv: out[b][l][o](+rowOff) = sum_t sum_c W[b][t][o][c] * Xt[b][l+t][c]
// K = 768 (12 tiles of 64: tap t = kt>>2, c0 = (kt&3)*64). M=256 (o), N=256 (l)/tile.
__global__ __launch_bounds__(512, 2) void k_conv(const bf16* __restrict__ Xt, const bf16* __restrict__ W,
                                                 const float* __restrict__ bias, bf16* __restrict__ out,
                                                 int outBatchStride, int outRowOff, int applyRelu,
                                                 float* __restrict__ statSum, float* __restrict__ statSq)
{
  __shared__ bf16 sAll[4*16384];
  const int b = blockIdx.z, l0 = blockIdx.x*256;
  const int tid = threadIdx.x, lane = tid & 63, wid = tid >> 6;
  const int wr = wid >> 2, wc = wid & 3;
  const int frow = lane & 15, g = lane >> 4;
  f32x4 acc[8][4] = {};

#define CONV_STAGE(kt, bufi) { \
    const int tt = (kt) >> 2, c0 = ((kt) & 3)*64; \
    const bf16* Ab = W  + (((size_t)b*3 + tt)*256)*256 + c0; \
    const bf16* Bb = Xt + ((size_t)b*4098 + l0 + tt)*256 + c0; \
    _Pragma("unroll") \
    for (int j = 0; j < 4; ++j){ \
      const int slot = tid + j*512, r = slot >> 3, s7 = slot & 7; \
      const int cc = (s7 ^ (r & 7)) * 8; \
      gload16(Ab + (size_t)r*256 + cc, &sAll[(bufi)*16384 + slot*8]); \
    } \
    _Pragma("unroll") \
    for (int j = 0; j < 4; ++j){ \
      const int slot = tid + j*512, r = slot >> 3, s7 = slot & 7; \
      const int cc = (s7 ^ (r & 7)) * 8; \
      gload16(Bb + (size_t)r*256 + cc, &sAll[32768 + (bufi)*16384 + slot*8]); \
    } \
  }

  CONV_STAGE(0, 0);
  #pragma unroll 1
  for (int kt = 0; kt < 12; ++kt){
    const int buf = kt & 1;
    if (kt + 1 < 12){
      CONV_STAGE(kt+1, buf^1);
      asm volatile("s_waitcnt vmcnt(8)" ::: "memory");
    } else {
      asm volatile("s_waitcnt vmcnt(0)" ::: "memory");
    }
    __builtin_amdgcn_s_barrier();
    __builtin_amdgcn_sched_barrier(0);
    const bf16* pA = sAll + buf*16384;
    const bf16* pB = sAll + 32768 + buf*16384;
    #pragma unroll
    for (int ks = 0; ks < 2; ++ks){
      short8 bfr[4];
      #pragma unroll
      for (int n = 0; n < 4; ++n){
        const int row = wc*64 + n*16 + frow;
        const int sl = (ks*4 + g) ^ (row & 7);
        bfr[n] = *reinterpret_cast<const short8*>(pB + row*64 + sl*8);
      }
      __builtin_amdgcn_s_setprio(1);
      #pragma unroll
      for (int m = 0; m < 8; ++m){
        const int row = wr*128 + m*16 + frow;
        const int sl = (ks*4 + g) ^ (row & 7);
        const short8 af = *reinterpret_cast<const short8*>(pA + row*64 + sl*8);
        #pragma unroll
        for (int n = 0; n < 4; ++n)
          acc[m][n] = __builtin_amdgcn_mfma_f32_16x16x32_bf16(af, bfr[n], acc[m][n], 0, 0, 0);
      }
      __builtin_amdgcn_s_setprio(0);
    }
    __builtin_amdgcn_sched_barrier(0);
    __builtin_amdgcn_s_barrier();
    __builtin_amdgcn_sched_barrier(0);
  }
#undef CONV_STAGE

  // epilogue: bias/relu/stats, acc -> swizzled LDS C-tile [256 l][256 o],
  // then full-line coalesced blast (no partial-line writes -> no L2 WA fill).
  float cs[8][4] = {{0.f}}, cq[8][4] = {{0.f}};
  #pragma unroll
  for (int m = 0; m < 8; ++m){
    const int col = wr*128 + m*16 + g*4;             // output channel o
    float bi[4] = {0.f, 0.f, 0.f, 0.f};
    if (bias){
      const f32x4 bv = *reinterpret_cast<const f32x4*>(bias + b*256 + col);
      bi[0]=bv[0]; bi[1]=bv[1]; bi[2]=bv[2]; bi[3]=bv[3];
    }
    #pragma unroll
    for (int n = 0; n < 4; ++n){
      const int row = wc*64 + n*16 + frow;           // l within tile
      float v[4];
      #pragma unroll
      for (int j = 0; j < 4; ++j){
        v[j] = acc[m][n][j] + bi[j];
        if (applyRelu) v[j] = fmaxf(v[j], 0.f);
        cs[m][j] += v[j];
        cq[m][j] += v[j]*v[j];
      }
      uint2v p;
      p[0] = (unsigned)f2b(v[0]) | ((unsigned)f2b(v[1]) << 16);
      p[1] = (unsigned)f2b(v[2]) | ((unsigned)f2b(v[3]) << 16);
      const int chunk = (col >> 3) ^ (row & 31);
      *reinterpret_cast<uint2v*>((char*)sAll + row*512 + chunk*16 + (g&1)*8) = p;
    }
  }
  __syncthreads();
  {
    char* gp = (char*)out + 2*((size_t)b*outBatchStride + (size_t)(l0 + outRowOff)*256);
    #pragma unroll
    for (int p2 = 0; p2 < 16; ++p2){
      const int row = p2*16 + (tid >> 5);
      const int c = tid & 31;
      const int cs2 = c ^ (row & 31);
      const uint4v v = *reinterpret_cast<const uint4v*>((const char*)sAll + row*512 + cs2*16);
      *reinterpret_cast<uint4v*>(gp + (size_t)row*512 + c*16) = v;
    }
  }
  if (statSum){
    #pragma unroll
    for (int m = 0; m < 8; ++m)
      #pragma unroll
      for (int j = 0; j < 4; ++j){
        #pragma unroll
        for (int d = 1; d < 16; d <<= 1){
          cs[m][j] += __shfl_xor(cs[m][j], d);
          cq[m][j] += __shfl_xor(cq[m][j], d);
        }
      }
    __syncthreads();                       // blast reads done -> LDS reusable
    float* ls = (float*)sAll;              // [8 waves][128 ch]
    float* lq = ls + 1024;
    if (frow == 0){
      #pragma unroll
      for (int m = 0; m < 8; ++m)
        #pragma unroll
        for (int j = 0; j < 4; ++j){
          ls[wid*128 + m*16 + g*4 + j] = cs[m][j];
          lq[wid*128 + m*16 + g*4 + j] = cq[m][j];
        }
    }
    __syncthreads();
    if (tid < 256){
      const int o = tid, half = o >> 7, idx = o & 127;
      float s = 0.f, qq = 0.f;
      #pragma unroll
      for (int wv = 0; wv < 4; ++wv){
        s  += ls[(half*4 + wv)*128 + idx];
        qq += lq[(half*4 + wv)*128 + idx];
      }
      atomicAdd(statSum + o, s);
      atomicAdd(statSq  + o, qq);
    }
  }
}

__global__ void k_bnfin(const float* __restrict__ sum, const float* __restrict__ sq,
                        const float* __restrict__ g, const float* __restrict__ bb,
                        float* __restrict__ scale, float* __restrict__ shift)
{
  const int o = threadIdx.x;
  const float inv = 1.f/65536.f;
  const float m = sum[o]*inv;
  const float v = fmaxf(sq[o]*inv - m*m, 0.f);
  const float sc = g[o] / sqrtf(v + 1e-5f);
  scale[o] = sc;
  shift[o] = bb[o] - m*sc;
}

// ---- h2T[b][lp][o] = relu(y2T[b][lp-1][o]*scale+shift), pads zeroed ----
__global__ __launch_bounds__(256) void k_norm2(const bf16* __restrict__ y, const float* __restrict__ scale,
                                               const float* __restrict__ shift, bf16* __restrict__ h)
{
  const int gr = blockIdx.x*8 + (threadIdx.x >> 5);
  const int oc = threadIdx.x & 31;
  const int b = gr / 4098, lp = gr - b*4098;
  unsigned short* dst = (unsigned short*)h + (size_t)gr*256 + oc*8;
  if (lp == 0 || lp == 4097){
    uint4v z = {0u,0u,0u,0u};
    *reinterpret_cast<uint4v*>(dst) = z;
    return;
  }
  const unsigned short* src = (const unsigned short*)y + ((size_t)b*4096 + (lp-1))*256 + oc*8;
  const uint4v in = *reinterpret_cast<const uint4v*>(src);
  const f32x4 sA0 = *reinterpret_cast<const f32x4*>(scale + oc*8);
  const f32x4 sA1 = *reinterpret_cast<const f32x4*>(scale + oc*8 + 4);
  const f32x4 hA0 = *reinterpret_cast<const f32x4*>(shift + oc*8);
  const f32x4 hA1 = *reinterpret_cast<const f32x4*>(shift + oc*8 + 4);
  uint4v ov;
  #pragma unroll
  for (int e = 0; e < 4; ++e){
    const unsigned int w = in[e];
    const float sc0 = (e<2) ? sA0[2*e] : sA1[2*e-4];
    const float sc1 = (e<2) ? sA0[2*e+1] : sA1[2*e-3];
    const float sh0 = (e<2) ? hA0[2*e] : hA1[2*e-4];
    const float sh1 = (e<2) ? hA0[2*e+1] : hA1[2*e-3];
    const float v0 = fmaxf(b2f((unsigned short)(w & 0xffffu))*sc0 + sh0, 0.f);
    const float v1 = fmaxf(b2f((unsigned short)(w >> 16))*sc1 + sh1, 0.f);
    ov[e] = (unsigned)f2b(v0) | ((unsigned)f2b(v1) << 16);
  }
  *reinterpret_cast<uint4v*>(dst) = ov;
}

// ---- h3 = relu(y3*scale+shift) in-place, plus per-(b,o) sums for SE ----
__global__ __launch_bounds__(256) void k_norm3(bf16* __restrict__ y, const float* __restrict__ scale,
                                               const float* __restrict__ shift, float* __restrict__ s_sum)
{
  __shared__ float red[8][256];
  const int tid = threadIdx.x;
  const int rr = tid >> 5, oc = tid & 31;
  const size_t row = (size_t)blockIdx.x*8 + rr;
  const int b = (int)(row >> 12);
  unsigned short* p = (unsigned short*)y + row*256 + oc*8;
  const uint4v in = *reinterpret_cast<const uint4v*>(p);
  const f32x4 sA0 = *reinterpret_cast<const f32x4*>(scale + oc*8);
  const f32x4 sA1 = *reinterpret_cast<const f32x4*>(scale + oc*8 + 4);
  const f32x4 hA0 = *reinterpret_cast<const f32x4*>(shift + oc*8);
  const f32x4 hA1 = *reinterpret_cast<const f32x4*>(shift + oc*8 + 4);
  uint4v ov;
  float loc[8];
  #pragma unroll
  for (int e = 0; e < 4; ++e){
    const unsigned int w = in[e];
    const float sc0 = (e<2) ? sA0[2*e] : sA1[2*e-4];
    const float sc1 = (e<2) ? sA0[2*e+1] : sA1[2*e-3];
    const float sh0 = (e<2) ? hA0[2*e] : hA1[2*e-4];
    const float sh1 = (e<2) ? hA0[2*e+1] : hA1[2*e-3];
    const float v0 = fmaxf(b2f((unsigned short)(w & 0xffffu))*sc0 + sh0, 0.f);
    const float v1 = fmaxf(b2f((unsigned short)(w >> 16))*sc1 + sh1, 0.f);
    loc[2*e] = v0; loc[2*e+1] = v1;
    ov[e] = (unsigned)f2b(v0) | ((unsigned)f2b(v1) << 16);
  }
  *reinterpret_cast<uint4v*>(p) = ov;
  #pragma unroll
  for (int j = 0; j < 8; ++j) red[rr][oc*8 + j] = loc[j];
  __syncthreads();
  const int o = tid;
  float tot = 0.f;
  #pragma unroll
  for (int r2 = 0; r2 < 8; ++r2) tot += red[r2][o];
  atomicAdd(&s_sum[(size_t)b*256 + o], tot);
}

// ---- SE: s2[b][o] = sigmoid(W2 @ relu(W1 @ mean + b1) + b2) ----
__global__ __launch_bounds__(256) void k_se(const float* __restrict__ s_sum, const float* __restrict__ w1,
                                            const float* __restrict__ b1, const float* __restrict__ w2,
                                            const float* __restrict__ b2, float* __restrict__ s2)
{
  __shared__ float sv[256];
  __shared__ float t1[256];
  const int b = blockIdx.x, o = threadIdx.x;
  sv[o] = s_sum[(size_t)b*256 + o] * (1.f/4096.f);
  __syncthreads();
  float a = b1[o];
  for (int c = 0; c < 256; ++c) a += w1[(size_t)o*256 + c] * sv[c];
  t1[o] = fmaxf(a, 0.f);
  __syncthreads();
  float a2 = b2[o];
  for (int c = 0; c < 256; ++c) a2 += w2[(size_t)o*256 + c] * t1[c];
  s2[(size_t)b*256 + o] = 1.f / (1.f + expf(-a2));
}

// ---- out[b][o][l] = relu(h3T[b][l][o]*s2[b][o] + x[b][o][l]) ----
__global__ __launch_bounds__(256) void k_final(const bf16* __restrict__ h3, const float* __restrict__ s2,
                                               const float* __restrict__ x, float* __restrict__ out)
{
  __shared__ float tile[64][65];
  const int b = blockIdx.z, o0 = blockIdx.y*64, l0 = blockIdx.x*64;
  const int tid = threadIdx.x;
  {
    const int r = tid >> 2, q = tid & 3;
    const unsigned short* src = (const unsigned short*)h3 + ((size_t)b*4096 + l0 + r)*256 + o0 + q*16;
    const uint4v a0 = *reinterpret_cast<const uint4v*>(src);
    const uint4v a1 = *reinterpret_cast<const uint4v*>(src + 8);
    #pragma unroll
    for (int e = 0; e < 4; ++e){
      tile[r][q*16 + 2*e]         = b2f((unsigned short)(a0[e] & 0xffffu));
      tile[r][q*16 + 2*e + 1]     = b2f((unsigned short)(a0[e] >> 16));
      tile[r][q*16 + 8 + 2*e]     = b2f((unsigned short)(a1[e] & 0xffffu));
      tile[r][q*16 + 8 + 2*e + 1] = b2f((unsigned short)(a1[e] >> 16));
    }
  }
  __syncthreads();
  {
    const int orow = tid >> 2, q = tid & 3;
    const int o = o0 + orow;
    const float sc = s2[(size_t)b*256 + o];
    const float* xs = x + ((size_t)b*256 + o)*4096 + l0 + q*16;
    float* dst = out + ((size_t)b*256 + o)*4096 + l0 + q*16;
    #pragma unroll
    for (int k = 0; k < 16; k += 4){
      const f32x4 xv = *reinterpret_cast<const f32x4*>(xs + k);
      f32x4 r;
      #pragma unroll
      for (int e = 0; e < 4; ++e)
        r[e] = fmaxf(tile[q*16 + k + e][orow]*sc + xv[e], 0.f);
      *reinterpret_cast<f32x4*>(dst + k) = r;
    }
  }
}

extern "C" void kernel_launch(void* const* d_in, const int* in_sizes, int n_in,
                              void* d_out, int out_size, void* d_ws, size_t ws_size,
                              hipStream_t stream)
{
  const float* x     = (const float*)d_in[0];
  const float* att1  = (const float*)d_in[1];
  const float* att2  = (const float*)d_in[2];
  const float* att3  = (const float*)d_in[3];
  const float* w1_w  = (const float*)d_in[4];
  const float* w1_b  = (const float*)d_in[5];
  const float* w2_w  = (const float*)d_in[6];
  const float* w2_b  = (const float*)d_in[7];
  const float* w3_w  = (const float*)d_in[8];
  const float* w3_b  = (const float*)d_in[9];
  const float* b1_w  = (const float*)d_in[10];
  const float* b1_b  = (const float*)d_in[11];
  const float* bn2_w = (const float*)d_in[12];
  const float* bn2_b = (const float*)d_in[13];
  const float* bn3_w = (const float*)d_in[14];
  const float* bn3_b = (const float*)d_in[15];
  const float* se1_w = (const float*)d_in[16];
  const float* se1_b = (const float*)d_in[17];
  const float* se2_w = (const float*)d_in[18];
  const float* se2_b = (const float*)d_in[19];

  char* ws = (char*)d_ws;
  // workspace layout (bytes)
  bf16*  xT   = (bf16*)(ws + 0);           // [16][4098][256]  (reused as y3T/h3T)
  bf16*  h1T  = (bf16*)(ws + 33570816);    // [16][4098][256]
  bf16*  y2T  = (bf16*)(ws + 67141632);    // [16][4096][256]
  bf16*  h2T  = (bf16*)(ws + 100696064);   // [16][4098][256]
  bf16*  Wt   = (bf16*)(ws + 134266880);   // [3][16][3][256][256]
  bf16*  attb = (bf16*)(ws + 153141248);   // [3][4096][1024]
  bf16*  wb   = (bf16*)(ws + 178307072);   // [3][768][1024]
  float* b1v  = (float*)(ws + 183025664);  // [4096]
  float* st   = (float*)(ws + 183042048);
  float* bn2sum = st;          // 256
  float* bn2sq  = st + 256;
  float* bn3sum = st + 512;
  float* bn3sq  = st + 768;
  float* s_sum  = st + 1024;   // 4096
  float* scale2 = st + 5120;
  float* shift2 = st + 5376;
  float* scale3 = st + 5632;
  float* shift3 = st + 5888;
  float* s2v    = st + 6144;   // 4096
  bf16*  y3T  = (bf16*)(ws + 0);           // overlay on xT (dead after conv1)

  // zero accumulators (bn2/bn3 sums + s_sum = 5120 floats)
  hipMemsetAsync(st, 0, 5120*sizeof(float), stream);

  k_transpose_x<<<dim3(64,4,16),256,0,stream>>>(x, xT);
  k_zero_pads<<<16,256,0,stream>>>(xT, h1T);
  k_cvt3<<<2048,256,0,stream>>>(att1, att2, att3, attb, 4096*1024);
  k_cvt3<<<512,256,0,stream>>>(w1_w, w2_w, w3_w, wb, 768*1024);
  k_gen<<<dim3(16,1,9),512,0,stream>>>(attb, wb, w1_b, w2_b, w3_b, Wt);
  k_b1<<<1024,256,0,stream>>>(att1, b1_w, b1_b, b1v);

  k_conv<<<dim3(16,1,16),512,0,stream>>>(xT,  Wt,                           b1v,     h1T, 4098*256, 1, 1, nullptr, nullptr);
  k_conv<<<dim3(16,1,16),512,0,stream>>>(h1T, Wt + (size_t)1*16*3*256*256,  nullptr, y2T, 4096*256, 0, 0, bn2sum, bn2sq);
  k_bnfin<<<1,256,0,stream>>>(bn2sum, bn2sq, bn2_w, bn2_b, scale2, shift2);
  k_norm2<<<8196,256,0,stream>>>(y2T, scale2, shift2, h2T);
  k_conv<<<dim3(16,1,16),512,0,stream>>>(h2T, Wt + (size_t)2*16*3*256*256,  nullptr, y3T, 4096*256, 0, 0, bn3sum, bn3sq);
  k_bnfin<<<1,256,0,stream>>>(bn3sum, bn3sq, bn3_w, bn3_b, scale3, shift3);
  k_norm3<<<8192,256,0,stream>>>(y3T, scale3, shift3, s_sum);
  k_se<<<16,256,0,stream>>>(s_sum, se1_w, se1_b, se2_w, se2_b, s2v);
  k_final<<<dim3(64,4,16),256,0,stream>>>((const bf16*)y3T, s2v, x, (float*)d_out);
}